// Round 11
// baseline (415.571 us; speedup 1.0000x reference)
//
#include <hip/hip_runtime.h>

#define NB 8
#define NC 64
#define NN 4096
#define NO 64
#define KK 20
#define EPSV 1e-5f
#define SLOPE 0.2f

typedef __attribute__((ext_vector_type(8))) short short8x;
typedef __attribute__((ext_vector_type(4))) float float4x;

// ws layout (float words):
// y1   : [B][N][O]            @0         2097152
// y2   : [B][N][O]            @2097152   2097152
// xx   : [B][N]               @4194304   32768
// keyu : [B][N][2][20] u32    @4227072   1310720
// idxu : [B][N][2][20] u16    @5537792   655360 words
// wa   : [C][O]               @6193152   4096
// wb   : [C][O]               @6197248   4096
// xThi : [B][N][C] bf16       @6201344   1048576
// xTmid: [B][N][C] bf16       @7249920   1048576
// xTlo : [B][N][C] bf16       @8298496   1048576

__device__ __forceinline__ unsigned short bfh(float f) {  // fp32 -> bf16 (RNE)
  unsigned u = __float_as_uint(f);
  unsigned r = u + 0x7FFFu + ((u >> 16) & 1u);
  return (unsigned short)(r >> 16);
}

__device__ __forceinline__ unsigned flipf(float f) {
  unsigned u = __float_as_uint(f);
  return u ^ ((unsigned)((int)u >> 31) | 0x80000000u);
}

// inverse of flipf, on raw flipped bits -> float bits
__device__ __forceinline__ unsigned unflipu(unsigned v) {
  return v ^ (0x80000000u | (unsigned)((int)(~v) >> 31));
}

__global__ void k0_wprep(const float* __restrict__ W,
                         float* __restrict__ wa, float* __restrict__ wb) {
  int t = threadIdx.x;
  for (int i = t; i < NC * NO; i += 256) {
    int o = i & 63, c = i >> 6;
    float w1 = W[o * 128 + c];
    float w2 = W[o * 128 + 64 + c];
    wa[i] = w1 - w2;  // [c][o]
    wb[i] = w2;
  }
}

__global__ __launch_bounds__(256) void k1_feat(const float* __restrict__ x,
    const float* __restrict__ waT, const float* __restrict__ wbT,
    float* __restrict__ y1, float* __restrict__ y2, float* __restrict__ xxg,
    unsigned short* __restrict__ xThi, unsigned short* __restrict__ xTmid,
    unsigned short* __restrict__ xTlo) {
  __shared__ __align__(16) float xs[NC * 68];   // [c][n] stride 68
  __shared__ __align__(16) float wa[NC * NO];
  __shared__ __align__(16) float wb[NC * NO];
  int t = threadIdx.x;
  int b = blockIdx.x >> 6;
  int gr0 = (blockIdx.x & 63) << 6;
  const float* xb = x + (size_t)b * NC * NN;
  #pragma unroll
  for (int k = 0; k < 4; ++k) {
    int i4 = t + k * 256;
    int c = i4 >> 4, col4 = (i4 & 15) << 2;
    *(float4*)&xs[c * 68 + col4] = *(const float4*)&xb[(size_t)c * NN + gr0 + col4];
    *(float4*)&wa[c * 64 + col4] = *(const float4*)&waT[c * 64 + col4];
    *(float4*)&wb[c * 64 + col4] = *(const float4*)&wbT[c * 64 + col4];
  }
  __syncthreads();
  if (t < 64) {
    float s = 0.f;
    #pragma unroll
    for (int c = 0; c < NC; ++c) { float v = xs[c * 68 + t]; s = fmaf(v, v, s); }
    xxg[b * NN + gr0 + t] = s;
  }
  int o = t & 63, w = t >> 6;
  for (int j = 0; j < 16; ++j) {
    int n = j * 4 + w;
    float a1 = 0.f, a2 = 0.f;
    #pragma unroll
    for (int c = 0; c < NC; ++c) {
      float xv = xs[c * 68 + n];
      a1 = fmaf(wa[c * 64 + o], xv, a1);
      a2 = fmaf(wb[c * 64 + o], xv, a2);
    }
    size_t base = ((size_t)b * NN + gr0 + n) * NO + o;
    y1[base] = a1;
    y2[base] = a2;
  }
  // 3-level bf16 split (REQUIRED: 2-level flips top-K selections, R10 failed),
  // transposed layout xT[b][n][c]
  int n2 = t >> 2, c0 = (t & 3) << 4;
  short8x vh[2], vm[2], vl[2];
  #pragma unroll
  for (int i = 0; i < 16; ++i) {
    float v = xs[(c0 + i) * 68 + n2];
    unsigned short h = bfh(v);
    float hf = __uint_as_float((unsigned)h << 16);
    float r1 = v - hf;
    unsigned short md = bfh(r1);
    float mf = __uint_as_float((unsigned)md << 16);
    unsigned short lo = bfh(r1 - mf);
    vh[i >> 3][i & 7] = (short)h;
    vm[i >> 3][i & 7] = (short)md;
    vl[i >> 3][i & 7] = (short)lo;
  }
  size_t tb = ((size_t)(b * NN + gr0 + n2)) * 64 + c0;
  *(short8x*)&xThi[tb] = vh[0];  *(short8x*)&xThi[tb + 8] = vh[1];
  *(short8x*)&xTmid[tb] = vm[0]; *(short8x*)&xTmid[tb + 8] = vm[1];
  *(short8x*)&xTlo[tb] = vl[0];  *(short8x*)&xTlo[tb + 8] = vl[1];
}

// ----- MFMA split-bf16 Gram + per-row exact top-K (column half) -----
// grid 1024: blk = b*128 + rowgroup*2 + half (R7-proven ordering, 34MB fetch)
//
// R12 (291us): padded candU; R13 spill; R14 (305us); R15 (278us, BEST):
//   lane-local keys via swapped MFMA, no candU, VGPR 64, occ 33.5%.
// R16 (292us): DMA staging -> VGPR 80, occupancy cliff. R17 (290us): dbuf
//   DMA same. R18 (282us): 8-wave/128-row, occ 37% -- NO faster.
//   Conclusion: k2 is VALU-ISSUE-bound (VALU-busy time ~187us invariant);
//   occupancy >33% buys nothing. Cut instructions, not latency.
// R19 (this round): codegen-targeted VALU cuts on the R15 base:
//   (1) ds_read addressing: with n=16j+lm, 16j==0 (mod 8), so the swizzle
//       ((4ks+quad+n)&7) is j-INDEPENDENT. All 24 read addrs = base_ks
//       + j*2048 + lvl*8192 bytes: TWO dynamic bases + immediate offsets
//       -> ~0 addressing VALU/tile (was ~70/tile rematerialized under the
//       64-VGPR budget).
//   (2) literal zero C into the first MFMA per acc[j] (inline-0 foldable;
//       bit-identical: 0+x in same adder tree; per-acc op order preserved
//       ks0's 6 then ks1's 6).
//   (3) insert loop: explicitly carried compare -> exactly 1 u64 cmp +
//       4 cndmask per step (guaranteed CSE).
//   VGPR tripwire: must stay <=64 (else occupancy cliff). WRITE ~10.2MB.
//   Gram numerics FROZEN (no MFMA shape/order changes, R10 lesson).
__global__ __launch_bounds__(256, 3) void k2_topk(
    const unsigned short* __restrict__ xThi, const unsigned short* __restrict__ xTmid,
    const unsigned short* __restrict__ xTlo, const float* __restrict__ xxg,
    unsigned* __restrict__ keyuG, unsigned short* __restrict__ idxG) {
  __shared__ __align__(16) unsigned short Rb[3 * 4096];  // 24KB staging hi/mid/lo;
                                                         // merge M u64[32*84]=21.5KB aliases
  __shared__ __align__(16) float xxs[64];

  int t = threadIdx.x;
  int blk = blockIdx.x;
  int b = blk >> 7;
  int rem = blk & 127;
  int rg = rem >> 1, half = rem & 1;
  int gr0 = rg << 6;
  int gc0 = half << 11;
  int w = t >> 6;                               // wave
  int lm = t & 15;                              // lane&15 -> row n = 16w+lm
  int quad = (t >> 4) & 3;                      // quarter: owns m ≡ 4q..4q+3 (mod 16)

  // persistent A-fragments (rows gr0+16w+lm, 3 levels x 2 k-steps)
  size_t abase = ((size_t)(b * NN + gr0 + 16 * w + lm)) * 64;
  short8x Ah[2], Am[2], Al[2];
  #pragma unroll
  for (int ks = 0; ks < 2; ++ks) {
    int co = ks * 32 + quad * 8;
    Ah[ks] = *(const short8x*)&xThi[abase + co];
    Am[ks] = *(const short8x*)&xTmid[abase + co];
    Al[ks] = *(const short8x*)&xTlo[abase + co];
  }

  unsigned long long lst[KK];                   // packed (flip(key)<<12)|m
  #pragma unroll
  for (int j = 0; j < KK; ++j) lst[j] = ~0ull;

  size_t bbase = (size_t)(b * NN) * 64;

  // R19(1): two dynamic LDS byte-bases; everything else immediate.
  // byte addr(lvl,ks,j) = lvl*8192 + j*2048 + 128*lm + 16*((4ks+quad+lm)&7)
  const char* rb8 = (const char*)Rb;
  const char* base0 = rb8 + 128 * lm + 16 * ((quad + lm) & 7);       // ks=0
  const char* base1 = rb8 + 128 * lm + 16 * ((4 + quad + lm) & 7);   // ks=1

  for (int mt = 0; mt < 32; ++mt) {
    int gm0 = gc0 + (mt << 6);
    __syncthreads();  // (A) prev tile's Rb/xxs reads done
    #pragma unroll
    for (int lvl = 0; lvl < 3; ++lvl) {
      const unsigned short* src = (lvl == 0) ? xThi : (lvl == 1) ? xTmid : xTlo;
      unsigned short* dst = Rb + lvl * 4096;
      #pragma unroll
      for (int p = 0; p < 2; ++p) {
        int idx = p * 256 + t;
        int n = idx >> 3, o = idx & 7;
        *(short8x*)&dst[n * 64 + ((o + n) & 7) * 8] =
            *(const short8x*)&src[bbase + (size_t)(gm0 + n) * 64 + o * 8];
      }
    }
    if (t < 16) *(float4*)&xxs[t * 4] = *(const float4*)&xxg[b * NN + gm0 + t * 4];
    __syncthreads();  // (B) Rb + xxs ready

    // swapped operand order (R13): D col=lane&15 = n-row, row = m-col.
    // Per-acc chain: ks0's [bm·Am, bl·Ah, bh·Al, bm·Ah, bh·Am, bh·Ah] then
    // ks1's same -> identical accumulation order to R15 -> bit-identical.
    float4x acc[4];
    #pragma unroll
    for (int j = 0; j < 4; ++j) {
      short8x bh0 = *(const short8x*)(base0 + j * 2048);
      short8x bm0 = *(const short8x*)(base0 + j * 2048 + 8192);
      short8x bl0 = *(const short8x*)(base0 + j * 2048 + 16384);
      float4x a = __builtin_amdgcn_mfma_f32_16x16x32_bf16(
          bm0, Am[0], (float4x){0.f, 0.f, 0.f, 0.f}, 0, 0, 0);  // R19(2) zero-C
      a = __builtin_amdgcn_mfma_f32_16x16x32_bf16(bl0, Ah[0], a, 0, 0, 0);
      a = __builtin_amdgcn_mfma_f32_16x16x32_bf16(bh0, Al[0], a, 0, 0, 0);
      a = __builtin_amdgcn_mfma_f32_16x16x32_bf16(bm0, Ah[0], a, 0, 0, 0);
      a = __builtin_amdgcn_mfma_f32_16x16x32_bf16(bh0, Am[0], a, 0, 0, 0);
      a = __builtin_amdgcn_mfma_f32_16x16x32_bf16(bh0, Ah[0], a, 0, 0, 0);
      short8x bh1 = *(const short8x*)(base1 + j * 2048);
      short8x bm1 = *(const short8x*)(base1 + j * 2048 + 8192);
      short8x bl1 = *(const short8x*)(base1 + j * 2048 + 16384);
      a = __builtin_amdgcn_mfma_f32_16x16x32_bf16(bm1, Am[1], a, 0, 0, 0);
      a = __builtin_amdgcn_mfma_f32_16x16x32_bf16(bl1, Ah[1], a, 0, 0, 0);
      a = __builtin_amdgcn_mfma_f32_16x16x32_bf16(bh1, Al[1], a, 0, 0, 0);
      a = __builtin_amdgcn_mfma_f32_16x16x32_bf16(bm1, Ah[1], a, 0, 0, 0);
      a = __builtin_amdgcn_mfma_f32_16x16x32_bf16(bh1, Am[1], a, 0, 0, 0);
      a = __builtin_amdgcn_mfma_f32_16x16x32_bf16(bh1, Ah[1], a, 0, 0, 0);
      acc[j] = a;
    }

    // per-lane: acc[j][q] = Gram(n = gr0+16w+lm, m = gm0 + 16j + 4*quad + q)
    // threshold: min over the row's 4 quad-lanes of own 20th-best (float dom.)
    unsigned own19u = (unsigned)(lst[KK - 1] >> 12);
    own19u = min(own19u, 0xFF7FFFFFu);  // clamp sentinel -> FLT_MAX, not NaN
    float thr = __uint_as_float(unflipu(own19u));
    thr = fminf(thr, __shfl_xor(thr, 16));
    thr = fminf(thr, __shfl_xor(thr, 32));

    // mask only -- keys are NOT materialized (recomputed on the rare pop path)
    unsigned mask = 0;
    #pragma unroll
    for (int j = 0; j < 4; ++j) {
      float4 xq = *(const float4*)&xxs[16 * j + 4 * quad];  // broadcast b128
      const float* xqp = (const float*)&xq;
      #pragma unroll
      for (int q = 0; q < 4; ++q) {
        float kv = fmaf(-2.f, acc[j][q], xqp[q]);
        mask |= (unsigned)(kv <= thr) << (4 * j + q);
      }
    }

    // rare path, SINGLE insert site: row-level bound guarantees any
    // final-top-20 candidate passes; exact u64 check rejects extras.
    // key recomputed: 15-cndmask mux over acc + xxs[c] re-read (c = xxs idx).
    while (mask) {
      int e = __builtin_ctz(mask);
      mask &= mask - 1;
      float a00 = (e & 1) ? acc[0][1] : acc[0][0];
      float a01 = (e & 1) ? acc[0][3] : acc[0][2];
      float a10 = (e & 1) ? acc[1][1] : acc[1][0];
      float a11 = (e & 1) ? acc[1][3] : acc[1][2];
      float a20 = (e & 1) ? acc[2][1] : acc[2][0];
      float a21 = (e & 1) ? acc[2][3] : acc[2][2];
      float a30 = (e & 1) ? acc[3][1] : acc[3][0];
      float a31 = (e & 1) ? acc[3][3] : acc[3][2];
      float b0 = (e & 2) ? a01 : a00;
      float b1 = (e & 2) ? a11 : a10;
      float b2 = (e & 2) ? a21 : a20;
      float b3 = (e & 2) ? a31 : a30;
      float c0v = (e & 4) ? b1 : b0;
      float c1v = (e & 4) ? b3 : b2;
      float av = (e & 8) ? c1v : c0v;
      int c = ((e & 12) << 2) | (quad << 2) | (e & 3);  // = m_local = xxs idx
      float kv = fmaf(-2.f, av, xxs[c]);
      unsigned ku = flipf(kv);
      unsigned long long p = ((unsigned long long)ku << 12) | (unsigned)(gm0 + c);
      // R19(3): carried-compare chain: 1 u64 cmp + 4 cndmask per step.
      if (p < lst[KK - 1]) {
        bool cj = true;  // p < lst[19] (gate)
        #pragma unroll
        for (int jj = KK - 1; jj >= 1; --jj) {
          bool cj1 = p < lst[jj - 1];
          lst[jj] = cj1 ? lst[jj - 1] : (cj ? p : lst[jj]);
          cj = cj1;
        }
        if (cj) lst[0] = p;
      }
    }
  }

  // two-phase merge (rows 0-31, then 32-63): M = u64[32][84] aliases Rb (dead now)
  int orow = 16 * w + lm, oq = quad;            // owner (row, quarter)
  unsigned long long* M = (unsigned long long*)Rb;
  #pragma unroll 1
  for (int ph = 0; ph < 2; ++ph) {
    __syncthreads();
    if ((orow >> 5) == ph) {
      int r5 = orow & 31;
      #pragma unroll
      for (int k = 0; k < KK; ++k) M[r5 * 84 + oq * 21 + k] = lst[k];
      M[r5 * 84 + oq * 21 + KK] = ~0ull;
    }
    __syncthreads();
    if (t < 32) {
      int h0 = 0, h1 = 0, h2 = 0, h3 = 0;
      int rb = t * 84;
      int row = ph * 32 + t;
      size_t base = ((size_t)(b * NN + gr0 + row) * 2 + half) * KK;
      for (int k = 0; k < KK; ++k) {
        unsigned long long v0m = M[rb + h0];
        unsigned long long v1m = M[rb + 21 + h1];
        unsigned long long v2m = M[rb + 42 + h2];
        unsigned long long v3m = M[rb + 63 + h3];
        unsigned long long bv = v0m; int bq = 0;
        if (v1m < bv) { bv = v1m; bq = 1; }
        if (v2m < bv) { bv = v2m; bq = 2; }
        if (v3m < bv) { bv = v3m; bq = 3; }
        keyuG[base + k] = (unsigned)(bv >> 12);
        idxG[base + k] = (unsigned short)(bv & 0xFFFu);
        if (bq == 0) h0++; else if (bq == 1) h1++; else if (bq == 2) h2++; else h3++;
      }
    }
  }
}

__global__ __launch_bounds__(256) void k3_out(const float* __restrict__ y1,
    const float* __restrict__ y2, const unsigned* __restrict__ keyuG,
    const unsigned short* __restrict__ idxG,
    const float* __restrict__ gamma, const float* __restrict__ beta,
    const float* __restrict__ rmean, const float* __restrict__ rvar,
    float* __restrict__ out) {
  __shared__ int sidx[64 * KK];
  __shared__ float ot[64 * 65];  // [o][n], pad 65
  int t = threadIdx.x;
  int b = blockIdx.x >> 6;
  int gr0 = (blockIdx.x & 63) << 6;
  if (t < 64) {  // 2-way merge of column-half lists
    size_t base0 = ((size_t)(b * NN + gr0 + t) * 2) * KK;
    size_t base1 = base0 + KK;
    int h0 = 0, h1 = 0;
    for (int k = 0; k < KK; ++k) {
      int a0 = h0 < KK ? h0 : KK - 1;
      int a1 = h1 < KK ? h1 : KK - 1;
      unsigned k0v = keyuG[base0 + a0]; unsigned i0 = idxG[base0 + a0];
      unsigned k1v = keyuG[base1 + a1]; unsigned i1 = idxG[base1 + a1];
      bool take0 = (h1 >= KK) ||
                   ((h0 < KK) && (k0v < k1v || (k0v == k1v && i0 < i1)));
      sidx[t * KK + k] = take0 ? (int)i0 : (int)i1;
      if (take0) h0++; else h1++;
    }
  }
  int l = t & 63, w = t >> 6;
  float sc = gamma[l] * rsqrtf(rvar[l] + EPSV);
  float tt = fmaf(-rmean[l], sc, beta[l]);
  __syncthreads();
  const float* y2b = y2 + (size_t)b * NN * NO;
  for (int rr = 0; rr < 16; ++rr) {
    int row = w * 16 + rr;
    float v1 = y1[((size_t)b * NN + gr0 + row) * NO + l];
    int mk[KK];
    #pragma unroll
    for (int k = 0; k < KK; ++k) mk[k] = sidx[row * KK + k];
    float vv[KK];
    #pragma unroll
    for (int k = 0; k < KK; ++k) vv[k] = y2b[(size_t)mk[k] * NO + l];  // 20 in flight
    float best = -3.4e38f;
    #pragma unroll
    for (int k = 0; k < KK; ++k) {
      float v = v1 + vv[k];
      v = fmaf(v, sc, tt);
      v = v >= 0.f ? v : SLOPE * v;
      best = fmaxf(best, v);
    }
    ot[l * 65 + row] = best;
  }
  __syncthreads();
  float* ob = out + (size_t)b * NO * NN;
  for (int i = t; i < 4096; i += 256) {
    int o = i >> 6, n = i & 63;
    ob[(size_t)o * NN + gr0 + n] = ot[o * 65 + n];  // coalesced
  }
}

extern "C" void kernel_launch(void* const* d_in, const int* in_sizes, int n_in,
                              void* d_out, int out_size, void* d_ws, size_t ws_size,
                              hipStream_t stream) {
  const float* x     = (const float*)d_in[0];
  const float* W     = (const float*)d_in[1];
  const float* gamma = (const float*)d_in[2];
  const float* beta  = (const float*)d_in[3];
  const float* rmean = (const float*)d_in[4];
  const float* rvar  = (const float*)d_in[5];
  float* ws  = (float*)d_ws;
  float* y1    = ws;
  float* y2    = ws + 2097152;
  float* xx    = ws + 4194304;
  unsigned* keyu = (unsigned*)(ws + 4227072);
  unsigned short* idxu = (unsigned short*)(ws + 5537792);
  float* wa    = ws + 6193152;
  float* wb    = ws + 6197248;
  unsigned short* xThi  = (unsigned short*)(ws + 6201344);
  unsigned short* xTmid = (unsigned short*)(ws + 7249920);
  unsigned short* xTlo  = (unsigned short*)(ws + 8298496);
  float* out = (float*)d_out;

  hipLaunchKernelGGL(k0_wprep, dim3(1),    dim3(256), 0, stream, W, wa, wb);
  hipLaunchKernelGGL(k1_feat,  dim3(512),  dim3(256), 0, stream, x, wa, wb, y1, y2, xx,
                     xThi, xTmid, xTlo);
  hipLaunchKernelGGL(k2_topk,  dim3(1024), dim3(256), 0, stream, xThi, xTmid, xTlo,
                     xx, keyu, idxu);
  hipLaunchKernelGGL(k3_out,   dim3(512),  dim3(256), 0, stream, y1, y2, keyu, idxu,
                     gamma, beta, rmean, rvar, out);
}

// Round 12
// 407.989 us; speedup vs baseline: 1.0186x; 1.0186x over previous
//
#include <hip/hip_runtime.h>

#define NB 8
#define NC 64
#define NN 4096
#define NO 64
#define KK 20
#define EPSV 1e-5f
#define SLOPE 0.2f

typedef __attribute__((ext_vector_type(8))) short short8x;
typedef __attribute__((ext_vector_type(4))) float float4x;

// ws layout (float words):
// y1   : [B][N][O]            @0         2097152
// y2   : [B][N][O]            @2097152   2097152
// xx   : [B][N]               @4194304   32768
// keyu : [B][N][2][20] u32    @4227072   1310720
// idxu : [B][N][2][20] u16    @5537792   655360 words
// wa   : [C][O]               @6193152   4096
// wb   : [C][O]               @6197248   4096
// xThi : [B][N][C] bf16       @6201344   1048576
// xTmid: [B][N][C] bf16       @7249920   1048576
// xTlo : [B][N][C] bf16       @8298496   1048576

__device__ __forceinline__ unsigned short bfh(float f) {  // fp32 -> bf16 (RNE)
  unsigned u = __float_as_uint(f);
  unsigned r = u + 0x7FFFu + ((u >> 16) & 1u);
  return (unsigned short)(r >> 16);
}

__device__ __forceinline__ unsigned flipf(float f) {
  unsigned u = __float_as_uint(f);
  return u ^ ((unsigned)((int)u >> 31) | 0x80000000u);
}

// inverse of flipf, on raw flipped bits -> float bits
__device__ __forceinline__ unsigned unflipu(unsigned v) {
  return v ^ (0x80000000u | (unsigned)((int)(~v) >> 31));
}

__global__ void k0_wprep(const float* __restrict__ W,
                         float* __restrict__ wa, float* __restrict__ wb) {
  int t = threadIdx.x;
  for (int i = t; i < NC * NO; i += 256) {
    int o = i & 63, c = i >> 6;
    float w1 = W[o * 128 + c];
    float w2 = W[o * 128 + 64 + c];
    wa[i] = w1 - w2;  // [c][o]
    wb[i] = w2;
  }
}

__global__ __launch_bounds__(256) void k1_feat(const float* __restrict__ x,
    const float* __restrict__ waT, const float* __restrict__ wbT,
    float* __restrict__ y1, float* __restrict__ y2, float* __restrict__ xxg,
    unsigned short* __restrict__ xThi, unsigned short* __restrict__ xTmid,
    unsigned short* __restrict__ xTlo) {
  __shared__ __align__(16) float xs[NC * 68];   // [c][n] stride 68
  __shared__ __align__(16) float wa[NC * NO];
  __shared__ __align__(16) float wb[NC * NO];
  int t = threadIdx.x;
  int b = blockIdx.x >> 6;
  int gr0 = (blockIdx.x & 63) << 6;
  const float* xb = x + (size_t)b * NC * NN;
  #pragma unroll
  for (int k = 0; k < 4; ++k) {
    int i4 = t + k * 256;
    int c = i4 >> 4, col4 = (i4 & 15) << 2;
    *(float4*)&xs[c * 68 + col4] = *(const float4*)&xb[(size_t)c * NN + gr0 + col4];
    *(float4*)&wa[c * 64 + col4] = *(const float4*)&waT[c * 64 + col4];
    *(float4*)&wb[c * 64 + col4] = *(const float4*)&wbT[c * 64 + col4];
  }
  __syncthreads();
  if (t < 64) {
    float s = 0.f;
    #pragma unroll
    for (int c = 0; c < NC; ++c) { float v = xs[c * 68 + t]; s = fmaf(v, v, s); }
    xxg[b * NN + gr0 + t] = s;
  }
  int o = t & 63, w = t >> 6;
  for (int j = 0; j < 16; ++j) {
    int n = j * 4 + w;
    float a1 = 0.f, a2 = 0.f;
    #pragma unroll
    for (int c = 0; c < NC; ++c) {
      float xv = xs[c * 68 + n];
      a1 = fmaf(wa[c * 64 + o], xv, a1);
      a2 = fmaf(wb[c * 64 + o], xv, a2);
    }
    size_t base = ((size_t)b * NN + gr0 + n) * NO + o;
    y1[base] = a1;
    y2[base] = a2;
  }
  // 3-level bf16 split (REQUIRED: 2-level flips top-K selections, R10 failed),
  // transposed layout xT[b][n][c]
  int n2 = t >> 2, c0 = (t & 3) << 4;
  short8x vh[2], vm[2], vl[2];
  #pragma unroll
  for (int i = 0; i < 16; ++i) {
    float v = xs[(c0 + i) * 68 + n2];
    unsigned short h = bfh(v);
    float hf = __uint_as_float((unsigned)h << 16);
    float r1 = v - hf;
    unsigned short md = bfh(r1);
    float mf = __uint_as_float((unsigned)md << 16);
    unsigned short lo = bfh(r1 - mf);
    vh[i >> 3][i & 7] = (short)h;
    vm[i >> 3][i & 7] = (short)md;
    vl[i >> 3][i & 7] = (short)lo;
  }
  size_t tb = ((size_t)(b * NN + gr0 + n2)) * 64 + c0;
  *(short8x*)&xThi[tb] = vh[0];  *(short8x*)&xThi[tb + 8] = vh[1];
  *(short8x*)&xTmid[tb] = vm[0]; *(short8x*)&xTmid[tb + 8] = vm[1];
  *(short8x*)&xTlo[tb] = vl[0];  *(short8x*)&xTlo[tb + 8] = vl[1];
}

// ----- MFMA split-bf16 Gram + per-row exact top-K (column half) -----
// grid 1024: blk = b*128 + rowgroup*2 + half (R7-proven ordering, 34MB fetch)
//
// R15 (278us, BEST): lane-local keys via swapped MFMA, no candU, VGPR 64,
//   occ 33.5%. R16 (292us) DMA staging: occ cliff. R17 (290us) dbuf: k2 not
//   latency-bound. R18 (282us) 8-wave: occ 37% no gain. => VALU-ISSUE-bound.
// R19 (322us) FAILED: j-outer MFMA restructure serialized the 4 independent
//   6-chains into 12-deep dependent chains (MfmaUtil 14.7->13.2) and char*
//   LDS casts degraded addressing. Lesson: R15's ks-outer/j-inner interleave
//   and plain ushort* indexing are load-bearing.
// R20 (this round): R15 base + independently-safe VALU cuts:
//   (1) tile-0 bitonic seed: 16 always-pass candidates packed into lst[0..15]
//       + 80-CE in-register bitonic sort (~450 VALU) replaces 16 sequential
//       20-deep chains (~2.4k VALU). Distinct u64s -> sorted result identical
//       to sequential inserts -> bit-identical.
//   (2) carried-compare insert chain: 1 u64 cmp + 4 cndmask per step.
//   (3) zero-C first MFMA per acc[j]: two j-loops (ks=0, ks=1) preserving
//       4 independent 6-chains and exact R15 per-acc accumulation order.
//   (4) pointer-increment staging: 3 level pointers += 8192B/tile; p=1 chunk
//       at constant +4096B; ds_write offsets tile-invariant.
//   VGPR tripwire <=64 (else occ cliff). WRITE ~10.2MB. Gram numerics FROZEN.
__global__ __launch_bounds__(256, 3) void k2_topk(
    const unsigned short* __restrict__ xThi, const unsigned short* __restrict__ xTmid,
    const unsigned short* __restrict__ xTlo, const float* __restrict__ xxg,
    unsigned* __restrict__ keyuG, unsigned short* __restrict__ idxG) {
  __shared__ __align__(16) unsigned short Rb[3 * 4096];  // 24KB staging hi/mid/lo;
                                                         // merge M u64[32*84]=21.5KB aliases
  __shared__ __align__(16) float xxs[64];

  int t = threadIdx.x;
  int blk = blockIdx.x;
  int b = blk >> 7;
  int rem = blk & 127;
  int rg = rem >> 1, half = rem & 1;
  int gr0 = rg << 6;
  int gc0 = half << 11;
  int w = t >> 6;                               // wave
  int lm = t & 15;                              // lane&15 -> row n = 16w+lm
  int quad = (t >> 4) & 3;                      // quarter: owns m ≡ 4q..4q+3 (mod 16)

  // persistent A-fragments (rows gr0+16w+lm, 3 levels x 2 k-steps)
  size_t abase = ((size_t)(b * NN + gr0 + 16 * w + lm)) * 64;
  short8x Ah[2], Am[2], Al[2];
  #pragma unroll
  for (int ks = 0; ks < 2; ++ks) {
    int co = ks * 32 + quad * 8;
    Ah[ks] = *(const short8x*)&xThi[abase + co];
    Am[ks] = *(const short8x*)&xTmid[abase + co];
    Al[ks] = *(const short8x*)&xTlo[abase + co];
  }

  unsigned long long lst[KK];                   // packed (flip(key)<<12)|m
  #pragma unroll
  for (int j = 0; j < KK; ++j) lst[j] = ~0ull;

  // R20(4): staging via incrementing pointers. Thread t stages chunk rows
  // n0 = t>>3 (p=0) and n0+32 (p=1), global word o = t&7.
  // dst slot: n*64 + ((o+n)&7)*8; for p=1, (o+n0+32)&7 == (o+n0)&7,
  // so dsl1 = dsl0 + 2048 (shorts). Global p=1 offset = +2048 shorts.
  int n0 = t >> 3, o8 = t & 7;
  size_t g0 = (size_t)(b * NN) * 64 + (size_t)(gc0 + n0) * 64 + o8 * 8;
  const unsigned short* gh = xThi + g0;
  const unsigned short* gmd = xTmid + g0;
  const unsigned short* gl = xTlo + g0;
  int dsl0 = n0 * 64 + ((o8 + n0) & 7) * 8;

  for (int mt = 0; mt < 32; ++mt) {
    int gm0 = gc0 + (mt << 6);
    __syncthreads();  // (A) prev tile's Rb/xxs reads done
    *(short8x*)&Rb[dsl0]          = *(const short8x*)gh;
    *(short8x*)&Rb[dsl0 + 2048]   = *(const short8x*)(gh + 2048);
    *(short8x*)&Rb[4096 + dsl0]        = *(const short8x*)gmd;
    *(short8x*)&Rb[4096 + dsl0 + 2048] = *(const short8x*)(gmd + 2048);
    *(short8x*)&Rb[8192 + dsl0]        = *(const short8x*)gl;
    *(short8x*)&Rb[8192 + dsl0 + 2048] = *(const short8x*)(gl + 2048);
    gh += 4096; gmd += 4096; gl += 4096;        // next tile: +64 rows
    if (t < 16) *(float4*)&xxs[t * 4] = *(const float4*)&xxg[b * NN + gm0 + t * 4];
    __syncthreads();  // (B) Rb + xxs ready

    // swapped operand order (R13): D col=lane&15 = n-row, row = m-col.
    // R20(3): ks=0 loop seeds acc[j] with literal-zero C (foldable); ks=1
    // loop extends. Per-acc order identical to R15 (ks0's 6 then ks1's 6).
    const unsigned short* RbH = Rb;
    const unsigned short* RbM = Rb + 4096;
    const unsigned short* RbL = Rb + 8192;
    float4x acc[4];
    #pragma unroll
    for (int j = 0; j < 4; ++j) {
      int n = 16 * j + lm;
      int off = n * 64 + ((quad + n) & 7) * 8;  // ks=0
      short8x bh = *(const short8x*)&RbH[off];
      short8x bm = *(const short8x*)&RbM[off];
      short8x bl = *(const short8x*)&RbL[off];
      float4x a = __builtin_amdgcn_mfma_f32_16x16x32_bf16(
          bm, Am[0], (float4x){0.f, 0.f, 0.f, 0.f}, 0, 0, 0);
      a = __builtin_amdgcn_mfma_f32_16x16x32_bf16(bl, Ah[0], a, 0, 0, 0);
      a = __builtin_amdgcn_mfma_f32_16x16x32_bf16(bh, Al[0], a, 0, 0, 0);
      a = __builtin_amdgcn_mfma_f32_16x16x32_bf16(bm, Ah[0], a, 0, 0, 0);
      a = __builtin_amdgcn_mfma_f32_16x16x32_bf16(bh, Am[0], a, 0, 0, 0);
      a = __builtin_amdgcn_mfma_f32_16x16x32_bf16(bh, Ah[0], a, 0, 0, 0);
      acc[j] = a;
    }
    #pragma unroll
    for (int j = 0; j < 4; ++j) {
      int n = 16 * j + lm;
      int off = n * 64 + ((4 + quad + n) & 7) * 8;  // ks=1
      short8x bh = *(const short8x*)&RbH[off];
      short8x bm = *(const short8x*)&RbM[off];
      short8x bl = *(const short8x*)&RbL[off];
      float4x a = acc[j];
      a = __builtin_amdgcn_mfma_f32_16x16x32_bf16(bm, Am[1], a, 0, 0, 0);
      a = __builtin_amdgcn_mfma_f32_16x16x32_bf16(bl, Ah[1], a, 0, 0, 0);
      a = __builtin_amdgcn_mfma_f32_16x16x32_bf16(bh, Al[1], a, 0, 0, 0);
      a = __builtin_amdgcn_mfma_f32_16x16x32_bf16(bm, Ah[1], a, 0, 0, 0);
      a = __builtin_amdgcn_mfma_f32_16x16x32_bf16(bh, Am[1], a, 0, 0, 0);
      a = __builtin_amdgcn_mfma_f32_16x16x32_bf16(bh, Ah[1], a, 0, 0, 0);
      acc[j] = a;
    }

    // per-lane: acc[j][q] = Gram(n = gr0+16w+lm, m = gm0 + 16j + 4*quad + q)
    if (mt == 0) {
      // R20(1): all 16 candidates pass (thr would be FLT_MAX). Pack into
      // lst[0..15] and bitonic-sort ascending in registers. lst[16..19]
      // remain sentinels -> identical to 16 sequential inserts.
      #pragma unroll
      for (int j = 0; j < 4; ++j) {
        float4 xq = *(const float4*)&xxs[16 * j + 4 * quad];
        const float* xqp = (const float*)&xq;
        #pragma unroll
        for (int q = 0; q < 4; ++q) {
          float kv = fmaf(-2.f, acc[j][q], xqp[q]);
          int c = 16 * j + (quad << 2) + q;
          lst[4 * j + q] =
              ((unsigned long long)flipf(kv) << 12) | (unsigned)(gm0 + c);
        }
      }
      #pragma unroll
      for (int k = 2; k <= 16; k <<= 1) {
        #pragma unroll
        for (int jj = k >> 1; jj > 0; jj >>= 1) {
          #pragma unroll
          for (int i = 0; i < 16; ++i) {
            int l2 = i ^ jj;
            if (l2 > i) {
              bool up = (i & k) == 0;
              unsigned long long x = lst[i], y = lst[l2];
              bool sw = up ? (x > y) : (x < y);
              unsigned long long lo = sw ? y : x;
              unsigned long long hi = sw ? x : y;
              lst[i] = lo; lst[l2] = hi;
            }
          }
        }
      }
    } else {
      // threshold: min over the row's 4 quad-lanes of own 20th-best
      unsigned own19u = (unsigned)(lst[KK - 1] >> 12);
      own19u = min(own19u, 0xFF7FFFFFu);  // clamp sentinel -> FLT_MAX not NaN
      float thr = __uint_as_float(unflipu(own19u));
      thr = fminf(thr, __shfl_xor(thr, 16));
      thr = fminf(thr, __shfl_xor(thr, 32));

      unsigned mask = 0;
      #pragma unroll
      for (int j = 0; j < 4; ++j) {
        float4 xq = *(const float4*)&xxs[16 * j + 4 * quad];  // broadcast b128
        const float* xqp = (const float*)&xq;
        #pragma unroll
        for (int q = 0; q < 4; ++q) {
          float kv = fmaf(-2.f, acc[j][q], xqp[q]);
          mask |= (unsigned)(kv <= thr) << (4 * j + q);
        }
      }

      // rare path, SINGLE insert site: row-level bound guarantees any
      // final-top-20 candidate passes; exact u64 check rejects extras.
      // key recomputed: 15-cndmask mux over acc + xxs[c] re-read.
      while (mask) {
        int e = __builtin_ctz(mask);
        mask &= mask - 1;
        float a00 = (e & 1) ? acc[0][1] : acc[0][0];
        float a01 = (e & 1) ? acc[0][3] : acc[0][2];
        float a10 = (e & 1) ? acc[1][1] : acc[1][0];
        float a11 = (e & 1) ? acc[1][3] : acc[1][2];
        float a20 = (e & 1) ? acc[2][1] : acc[2][0];
        float a21 = (e & 1) ? acc[2][3] : acc[2][2];
        float a30 = (e & 1) ? acc[3][1] : acc[3][0];
        float a31 = (e & 1) ? acc[3][3] : acc[3][2];
        float b0 = (e & 2) ? a01 : a00;
        float b1 = (e & 2) ? a11 : a10;
        float b2 = (e & 2) ? a21 : a20;
        float b3 = (e & 2) ? a31 : a30;
        float c0v = (e & 4) ? b1 : b0;
        float c1v = (e & 4) ? b3 : b2;
        float av = (e & 8) ? c1v : c0v;
        int c = ((e & 12) << 2) | (quad << 2) | (e & 3);  // = m_local = xxs idx
        float kv = fmaf(-2.f, av, xxs[c]);
        unsigned ku = flipf(kv);
        unsigned long long p = ((unsigned long long)ku << 12) | (unsigned)(gm0 + c);
        // R20(2): carried-compare chain: 1 u64 cmp + 4 cndmask per step.
        if (p < lst[KK - 1]) {
          bool cj = true;  // p < lst[19] (gate)
          #pragma unroll
          for (int jj = KK - 1; jj >= 1; --jj) {
            bool cj1 = p < lst[jj - 1];
            lst[jj] = cj1 ? lst[jj - 1] : (cj ? p : lst[jj]);
            cj = cj1;
          }
          if (cj) lst[0] = p;
        }
      }
    }
  }

  // two-phase merge (rows 0-31, then 32-63): M = u64[32][84] aliases Rb (dead now)
  int orow = 16 * w + lm, oq = quad;            // owner (row, quarter)
  unsigned long long* M = (unsigned long long*)Rb;
  #pragma unroll 1
  for (int ph = 0; ph < 2; ++ph) {
    __syncthreads();
    if ((orow >> 5) == ph) {
      int r5 = orow & 31;
      #pragma unroll
      for (int k = 0; k < KK; ++k) M[r5 * 84 + oq * 21 + k] = lst[k];
      M[r5 * 84 + oq * 21 + KK] = ~0ull;
    }
    __syncthreads();
    if (t < 32) {
      int h0 = 0, h1 = 0, h2 = 0, h3 = 0;
      int rb = t * 84;
      int row = ph * 32 + t;
      size_t base = ((size_t)(b * NN + gr0 + row) * 2 + half) * KK;
      for (int k = 0; k < KK; ++k) {
        unsigned long long v0m = M[rb + h0];
        unsigned long long v1m = M[rb + 21 + h1];
        unsigned long long v2m = M[rb + 42 + h2];
        unsigned long long v3m = M[rb + 63 + h3];
        unsigned long long bv = v0m; int bq = 0;
        if (v1m < bv) { bv = v1m; bq = 1; }
        if (v2m < bv) { bv = v2m; bq = 2; }
        if (v3m < bv) { bv = v3m; bq = 3; }
        keyuG[base + k] = (unsigned)(bv >> 12);
        idxG[base + k] = (unsigned short)(bv & 0xFFFu);
        if (bq == 0) h0++; else if (bq == 1) h1++; else if (bq == 2) h2++; else h3++;
      }
    }
  }
}

__global__ __launch_bounds__(256) void k3_out(const float* __restrict__ y1,
    const float* __restrict__ y2, const unsigned* __restrict__ keyuG,
    const unsigned short* __restrict__ idxG,
    const float* __restrict__ gamma, const float* __restrict__ beta,
    const float* __restrict__ rmean, const float* __restrict__ rvar,
    float* __restrict__ out) {
  __shared__ int sidx[64 * KK];
  __shared__ float ot[64 * 65];  // [o][n], pad 65
  int t = threadIdx.x;
  int b = blockIdx.x >> 6;
  int gr0 = (blockIdx.x & 63) << 6;
  if (t < 64) {  // 2-way merge of column-half lists
    size_t base0 = ((size_t)(b * NN + gr0 + t) * 2) * KK;
    size_t base1 = base0 + KK;
    int h0 = 0, h1 = 0;
    for (int k = 0; k < KK; ++k) {
      int a0 = h0 < KK ? h0 : KK - 1;
      int a1 = h1 < KK ? h1 : KK - 1;
      unsigned k0v = keyuG[base0 + a0]; unsigned i0 = idxG[base0 + a0];
      unsigned k1v = keyuG[base1 + a1]; unsigned i1 = idxG[base1 + a1];
      bool take0 = (h1 >= KK) ||
                   ((h0 < KK) && (k0v < k1v || (k0v == k1v && i0 < i1)));
      sidx[t * KK + k] = take0 ? (int)i0 : (int)i1;
      if (take0) h0++; else h1++;
    }
  }
  int l = t & 63, w = t >> 6;
  float sc = gamma[l] * rsqrtf(rvar[l] + EPSV);
  float tt = fmaf(-rmean[l], sc, beta[l]);
  __syncthreads();
  const float* y2b = y2 + (size_t)b * NN * NO;
  for (int rr = 0; rr < 16; ++rr) {
    int row = w * 16 + rr;
    float v1 = y1[((size_t)b * NN + gr0 + row) * NO + l];
    int mk[KK];
    #pragma unroll
    for (int k = 0; k < KK; ++k) mk[k] = sidx[row * KK + k];
    float vv[KK];
    #pragma unroll
    for (int k = 0; k < KK; ++k) vv[k] = y2b[(size_t)mk[k] * NO + l];  // 20 in flight
    float best = -3.4e38f;
    #pragma unroll
    for (int k = 0; k < KK; ++k) {
      float v = v1 + vv[k];
      v = fmaf(v, sc, tt);
      v = v >= 0.f ? v : SLOPE * v;
      best = fmaxf(best, v);
    }
    ot[l * 65 + row] = best;
  }
  __syncthreads();
  float* ob = out + (size_t)b * NO * NN;
  for (int i = t; i < 4096; i += 256) {
    int o = i >> 6, n = i & 63;
    ob[(size_t)o * NN + gr0 + n] = ot[o * 65 + n];  // coalesced
  }
}

extern "C" void kernel_launch(void* const* d_in, const int* in_sizes, int n_in,
                              void* d_out, int out_size, void* d_ws, size_t ws_size,
                              hipStream_t stream) {
  const float* x     = (const float*)d_in[0];
  const float* W     = (const float*)d_in[1];
  const float* gamma = (const float*)d_in[2];
  const float* beta  = (const float*)d_in[3];
  const float* rmean = (const float*)d_in[4];
  const float* rvar  = (const float*)d_in[5];
  float* ws  = (float*)d_ws;
  float* y1    = ws;
  float* y2    = ws + 2097152;
  float* xx    = ws + 4194304;
  unsigned* keyu = (unsigned*)(ws + 4227072);
  unsigned short* idxu = (unsigned short*)(ws + 5537792);
  float* wa    = ws + 6193152;
  float* wb    = ws + 6197248;
  unsigned short* xThi  = (unsigned short*)(ws + 6201344);
  unsigned short* xTmid = (unsigned short*)(ws + 7249920);
  unsigned short* xTlo  = (unsigned short*)(ws + 8298496);
  float* out = (float*)d_out;

  hipLaunchKernelGGL(k0_wprep, dim3(1),    dim3(256), 0, stream, W, wa, wb);
  hipLaunchKernelGGL(k1_feat,  dim3(512),  dim3(256), 0, stream, x, wa, wb, y1, y2, xx,
                     xThi, xTmid, xTlo);
  hipLaunchKernelGGL(k2_topk,  dim3(1024), dim3(256), 0, stream, xThi, xTmid, xTlo,
                     xx, keyu, idxu);
  hipLaunchKernelGGL(k3_out,   dim3(512),  dim3(256), 0, stream, y1, y2, keyu, idxu,
                     gamma, beta, rmean, rvar, out);
}

// Round 13
// 376.999 us; speedup vs baseline: 1.1023x; 1.0822x over previous
//
#include <hip/hip_runtime.h>

#define NB 8
#define NC 64
#define NN 4096
#define NO 64
#define KK 20
#define EPSV 1e-5f
#define SLOPE 0.2f

typedef __attribute__((ext_vector_type(8))) short short8x;
typedef __attribute__((ext_vector_type(4))) float float4x;

// ws layout (float words):
// y1   : [B][N][O]            @0         2097152
// y2   : [B][N][O]            @2097152   2097152
// xx   : [B][N]               @4194304   32768
// keyu : [B][N][2][20] u32    @4227072   1310720
// idxu : [B][N][2][20] u16    @5537792   655360 words
// wa   : [C][O]               @6193152   4096
// wb   : [C][O]               @6197248   4096
// xThi : [B][N][C] bf16       @6201344   1048576
// xTmid: [B][N][C] bf16       @7249920   1048576
// xTlo : [B][N][C] bf16       @8298496   1048576

__device__ __forceinline__ unsigned short bfh(float f) {  // fp32 -> bf16 (RNE)
  unsigned u = __float_as_uint(f);
  unsigned r = u + 0x7FFFu + ((u >> 16) & 1u);
  return (unsigned short)(r >> 16);
}

__device__ __forceinline__ unsigned flipf(float f) {
  unsigned u = __float_as_uint(f);
  return u ^ ((unsigned)((int)u >> 31) | 0x80000000u);
}

// inverse of flipf, on raw flipped bits -> float bits
__device__ __forceinline__ unsigned unflipu(unsigned v) {
  return v ^ (0x80000000u | (unsigned)((int)(~v) >> 31));
}

__global__ void k0_wprep(const float* __restrict__ W,
                         float* __restrict__ wa, float* __restrict__ wb) {
  int t = threadIdx.x;
  for (int i = t; i < NC * NO; i += 256) {
    int o = i & 63, c = i >> 6;
    float w1 = W[o * 128 + c];
    float w2 = W[o * 128 + 64 + c];
    wa[i] = w1 - w2;  // [c][o]
    wb[i] = w2;
  }
}

__global__ __launch_bounds__(256) void k1_feat(const float* __restrict__ x,
    const float* __restrict__ waT, const float* __restrict__ wbT,
    float* __restrict__ y1, float* __restrict__ y2, float* __restrict__ xxg,
    unsigned short* __restrict__ xThi, unsigned short* __restrict__ xTmid,
    unsigned short* __restrict__ xTlo) {
  __shared__ __align__(16) float xs[NC * 68];   // [c][n] stride 68
  __shared__ __align__(16) float wa[NC * NO];
  __shared__ __align__(16) float wb[NC * NO];
  int t = threadIdx.x;
  int b = blockIdx.x >> 6;
  int gr0 = (blockIdx.x & 63) << 6;
  const float* xb = x + (size_t)b * NC * NN;
  #pragma unroll
  for (int k = 0; k < 4; ++k) {
    int i4 = t + k * 256;
    int c = i4 >> 4, col4 = (i4 & 15) << 2;
    *(float4*)&xs[c * 68 + col4] = *(const float4*)&xb[(size_t)c * NN + gr0 + col4];
    *(float4*)&wa[c * 64 + col4] = *(const float4*)&waT[c * 64 + col4];
    *(float4*)&wb[c * 64 + col4] = *(const float4*)&wbT[c * 64 + col4];
  }
  __syncthreads();
  if (t < 64) {
    float s = 0.f;
    #pragma unroll
    for (int c = 0; c < NC; ++c) { float v = xs[c * 68 + t]; s = fmaf(v, v, s); }
    xxg[b * NN + gr0 + t] = s;
  }
  int o = t & 63, w = t >> 6;
  for (int j = 0; j < 16; ++j) {
    int n = j * 4 + w;
    float a1 = 0.f, a2 = 0.f;
    #pragma unroll
    for (int c = 0; c < NC; ++c) {
      float xv = xs[c * 68 + n];
      a1 = fmaf(wa[c * 64 + o], xv, a1);
      a2 = fmaf(wb[c * 64 + o], xv, a2);
    }
    size_t base = ((size_t)b * NN + gr0 + n) * NO + o;
    y1[base] = a1;
    y2[base] = a2;
  }
  // 3-level bf16 split (REQUIRED: 2-level flips top-K selections, R10 failed),
  // transposed layout xT[b][n][c]
  int n2 = t >> 2, c0 = (t & 3) << 4;
  short8x vh[2], vm[2], vl[2];
  #pragma unroll
  for (int i = 0; i < 16; ++i) {
    float v = xs[(c0 + i) * 68 + n2];
    unsigned short h = bfh(v);
    float hf = __uint_as_float((unsigned)h << 16);
    float r1 = v - hf;
    unsigned short md = bfh(r1);
    float mf = __uint_as_float((unsigned)md << 16);
    unsigned short lo = bfh(r1 - mf);
    vh[i >> 3][i & 7] = (short)h;
    vm[i >> 3][i & 7] = (short)md;
    vl[i >> 3][i & 7] = (short)lo;
  }
  size_t tb = ((size_t)(b * NN + gr0 + n2)) * 64 + c0;
  *(short8x*)&xThi[tb] = vh[0];  *(short8x*)&xThi[tb + 8] = vh[1];
  *(short8x*)&xTmid[tb] = vm[0]; *(short8x*)&xTmid[tb + 8] = vm[1];
  *(short8x*)&xTlo[tb] = vl[0];  *(short8x*)&xTlo[tb + 8] = vl[1];
}

// ----- MFMA split-bf16 Gram + per-row exact top-K (column half) -----
// grid 1024: blk = b*128 + rowgroup*2 + half (R7-proven ordering, 34MB fetch)
//
// FINAL (R21 = R15 byte-identical revert). Session ledger:
//   R12 (291us): padded candU scan. R13: spill (4 insert sites + key[16]).
//   R14 (305us): spill fixed, occupancy stuck. R15 (278us, BEST): lane-local
//   keys via swapped MFMA, no candU/cutq/barrier-C; VGPR 64 -> occ 33.5%.
//   R16 (292us): DMA staging -> VGPR 80 occupancy cliff (>=68 => 25.7%).
//   R17 (290us): one-barrier dbuf DMA -> k2 NOT staging-latency-bound.
//   R18 (282us): 8-wave/128-row, occ 37% -> no gain (VALU-issue-bound).
//   R19 (322us): j-outer MFMA + char* bases -> serialized MFMA chains.
//   R20 (310us): ks-split MFMA + bitonic seed + carried-compare -> same
//   schedule perturbation.
// Structural constraint (why this is the floor for this decomposition):
//   k2 is VALU-issue-bound in wave-serialized exact top-K maintenance
//   (K=20 in registers) + barrier-locked staging at the 33.5% occupancy the
//   64-VGPR budget allows. VALU-busy time ~188us invariant across every
//   occupancy/pipeline variant; every MFMA-loop reshape loses more to
//   compiler schedule perturbation than the VALU cut saves. R15's exact
//   code shape (ks-outer/j-inner interleave, plain ushort* LDS indexing,
//   common acc zero-init) is load-bearing.
__global__ __launch_bounds__(256, 3) void k2_topk(
    const unsigned short* __restrict__ xThi, const unsigned short* __restrict__ xTmid,
    const unsigned short* __restrict__ xTlo, const float* __restrict__ xxg,
    unsigned* __restrict__ keyuG, unsigned short* __restrict__ idxG) {
  __shared__ __align__(16) unsigned short Rb[3 * 4096];  // 24KB staging hi/mid/lo;
                                                         // merge M u64[32*84]=21.5KB aliases
  __shared__ __align__(16) float xxs[64];

  int t = threadIdx.x;
  int blk = blockIdx.x;
  int b = blk >> 7;
  int rem = blk & 127;
  int rg = rem >> 1, half = rem & 1;
  int gr0 = rg << 6;
  int gc0 = half << 11;
  int w = t >> 6;                               // wave
  int lm = t & 15;                              // lane&15 -> row n = 16w+lm
  int quad = (t >> 4) & 3;                      // quarter: owns m ≡ 4q..4q+3 (mod 16)

  // persistent A-fragments (rows gr0+16w+lm, 3 levels x 2 k-steps)
  size_t abase = ((size_t)(b * NN + gr0 + 16 * w + lm)) * 64;
  short8x Ah[2], Am[2], Al[2];
  #pragma unroll
  for (int ks = 0; ks < 2; ++ks) {
    int co = ks * 32 + quad * 8;
    Ah[ks] = *(const short8x*)&xThi[abase + co];
    Am[ks] = *(const short8x*)&xTmid[abase + co];
    Al[ks] = *(const short8x*)&xTlo[abase + co];
  }

  unsigned long long lst[KK];                   // packed (flip(key)<<12)|m
  #pragma unroll
  for (int j = 0; j < KK; ++j) lst[j] = ~0ull;

  size_t bbase = (size_t)(b * NN) * 64;

  for (int mt = 0; mt < 32; ++mt) {
    int gm0 = gc0 + (mt << 6);
    __syncthreads();  // (A) prev tile's Rb/xxs reads done
    #pragma unroll
    for (int lvl = 0; lvl < 3; ++lvl) {
      const unsigned short* src = (lvl == 0) ? xThi : (lvl == 1) ? xTmid : xTlo;
      unsigned short* dst = Rb + lvl * 4096;
      #pragma unroll
      for (int p = 0; p < 2; ++p) {
        int idx = p * 256 + t;
        int n = idx >> 3, o = idx & 7;
        *(short8x*)&dst[n * 64 + ((o + n) & 7) * 8] =
            *(const short8x*)&src[bbase + (size_t)(gm0 + n) * 64 + o * 8];
      }
    }
    if (t < 16) *(float4*)&xxs[t * 4] = *(const float4*)&xxg[b * NN + gm0 + t * 4];
    __syncthreads();  // (B) Rb + xxs ready

    float4x acc[4];
    #pragma unroll
    for (int j = 0; j < 4; ++j) acc[j] = (float4x){0.f, 0.f, 0.f, 0.f};

    const unsigned short* RbH = Rb;
    const unsigned short* RbM = Rb + 4096;
    const unsigned short* RbL = Rb + 8192;
    #pragma unroll
    for (int ks = 0; ks < 2; ++ks) {
      #pragma unroll
      for (int j = 0; j < 4; ++j) {
        int n = 16 * j + lm;
        int off = n * 64 + ((ks * 4 + quad + n) & 7) * 8;
        short8x bh = *(const short8x*)&RbH[off];
        short8x bm = *(const short8x*)&RbM[off];
        short8x bl = *(const short8x*)&RbL[off];
        // swapped operand order (R13): D col=lane&15 = n-row, row = m-col.
        // Same product pairs/order as before -> bit-identical sums.
        acc[j] = __builtin_amdgcn_mfma_f32_16x16x32_bf16(bm, Am[ks], acc[j], 0, 0, 0);
        acc[j] = __builtin_amdgcn_mfma_f32_16x16x32_bf16(bl, Ah[ks], acc[j], 0, 0, 0);
        acc[j] = __builtin_amdgcn_mfma_f32_16x16x32_bf16(bh, Al[ks], acc[j], 0, 0, 0);
        acc[j] = __builtin_amdgcn_mfma_f32_16x16x32_bf16(bm, Ah[ks], acc[j], 0, 0, 0);
        acc[j] = __builtin_amdgcn_mfma_f32_16x16x32_bf16(bh, Am[ks], acc[j], 0, 0, 0);
        acc[j] = __builtin_amdgcn_mfma_f32_16x16x32_bf16(bh, Ah[ks], acc[j], 0, 0, 0);
      }
    }

    // per-lane: acc[j][q] = Gram(n = gr0+16w+lm, m = gm0 + 16j + 4*quad + q)
    // threshold: min over the row's 4 quad-lanes of own 20th-best (float dom.)
    unsigned own19u = (unsigned)(lst[KK - 1] >> 12);
    own19u = min(own19u, 0xFF7FFFFFu);  // clamp sentinel -> FLT_MAX, not NaN
    float thr = __uint_as_float(unflipu(own19u));
    thr = fminf(thr, __shfl_xor(thr, 16));
    thr = fminf(thr, __shfl_xor(thr, 32));

    // mask only -- keys are NOT materialized (recomputed on the rare pop path)
    unsigned mask = 0;
    #pragma unroll
    for (int j = 0; j < 4; ++j) {
      float4 xq = *(const float4*)&xxs[16 * j + 4 * quad];  // broadcast b128
      const float* xqp = (const float*)&xq;
      #pragma unroll
      for (int q = 0; q < 4; ++q) {
        float kv = fmaf(-2.f, acc[j][q], xqp[q]);
        mask |= (unsigned)(kv <= thr) << (4 * j + q);
      }
    }

    // rare path, SINGLE insert site: row-level bound guarantees any
    // final-top-20 candidate passes; exact u64 check rejects extras.
    // key recomputed: 15-cndmask mux over acc + xxs[c] re-read (c = xxs idx).
    while (mask) {
      int e = __builtin_ctz(mask);
      mask &= mask - 1;
      float a00 = (e & 1) ? acc[0][1] : acc[0][0];
      float a01 = (e & 1) ? acc[0][3] : acc[0][2];
      float a10 = (e & 1) ? acc[1][1] : acc[1][0];
      float a11 = (e & 1) ? acc[1][3] : acc[1][2];
      float a20 = (e & 1) ? acc[2][1] : acc[2][0];
      float a21 = (e & 1) ? acc[2][3] : acc[2][2];
      float a30 = (e & 1) ? acc[3][1] : acc[3][0];
      float a31 = (e & 1) ? acc[3][3] : acc[3][2];
      float b0 = (e & 2) ? a01 : a00;
      float b1 = (e & 2) ? a11 : a10;
      float b2 = (e & 2) ? a21 : a20;
      float b3 = (e & 2) ? a31 : a30;
      float c0v = (e & 4) ? b1 : b0;
      float c1v = (e & 4) ? b3 : b2;
      float av = (e & 8) ? c1v : c0v;
      int c = ((e & 12) << 2) | (quad << 2) | (e & 3);  // = m_local = xxs idx
      float kv = fmaf(-2.f, av, xxs[c]);
      unsigned ku = flipf(kv);
      unsigned long long p = ((unsigned long long)ku << 12) | (unsigned)(gm0 + c);
      if (p < lst[KK - 1]) {
        #pragma unroll
        for (int jj = KK - 1; jj >= 1; --jj) {
          bool sh = p < lst[jj - 1];
          unsigned long long cur = (p < lst[jj]) ? p : lst[jj];
          lst[jj] = sh ? lst[jj - 1] : cur;
        }
        if (p < lst[0]) lst[0] = p;
      }
    }
  }

  // two-phase merge (rows 0-31, then 32-63): M = u64[32][84] aliases Rb (dead now)
  int orow = 16 * w + lm, oq = quad;            // owner (row, quarter)
  unsigned long long* M = (unsigned long long*)Rb;
  #pragma unroll 1
  for (int ph = 0; ph < 2; ++ph) {
    __syncthreads();
    if ((orow >> 5) == ph) {
      int r5 = orow & 31;
      #pragma unroll
      for (int k = 0; k < KK; ++k) M[r5 * 84 + oq * 21 + k] = lst[k];
      M[r5 * 84 + oq * 21 + KK] = ~0ull;
    }
    __syncthreads();
    if (t < 32) {
      int h0 = 0, h1 = 0, h2 = 0, h3 = 0;
      int rb = t * 84;
      int row = ph * 32 + t;
      size_t base = ((size_t)(b * NN + gr0 + row) * 2 + half) * KK;
      for (int k = 0; k < KK; ++k) {
        unsigned long long v0m = M[rb + h0];
        unsigned long long v1m = M[rb + 21 + h1];
        unsigned long long v2m = M[rb + 42 + h2];
        unsigned long long v3m = M[rb + 63 + h3];
        unsigned long long bv = v0m; int bq = 0;
        if (v1m < bv) { bv = v1m; bq = 1; }
        if (v2m < bv) { bv = v2m; bq = 2; }
        if (v3m < bv) { bv = v3m; bq = 3; }
        keyuG[base + k] = (unsigned)(bv >> 12);
        idxG[base + k] = (unsigned short)(bv & 0xFFFu);
        if (bq == 0) h0++; else if (bq == 1) h1++; else if (bq == 2) h2++; else h3++;
      }
    }
  }
}

__global__ __launch_bounds__(256) void k3_out(const float* __restrict__ y1,
    const float* __restrict__ y2, const unsigned* __restrict__ keyuG,
    const unsigned short* __restrict__ idxG,
    const float* __restrict__ gamma, const float* __restrict__ beta,
    const float* __restrict__ rmean, const float* __restrict__ rvar,
    float* __restrict__ out) {
  __shared__ int sidx[64 * KK];
  __shared__ float ot[64 * 65];  // [o][n], pad 65
  int t = threadIdx.x;
  int b = blockIdx.x >> 6;
  int gr0 = (blockIdx.x & 63) << 6;
  if (t < 64) {  // 2-way merge of column-half lists
    size_t base0 = ((size_t)(b * NN + gr0 + t) * 2) * KK;
    size_t base1 = base0 + KK;
    int h0 = 0, h1 = 0;
    for (int k = 0; k < KK; ++k) {
      int a0 = h0 < KK ? h0 : KK - 1;
      int a1 = h1 < KK ? h1 : KK - 1;
      unsigned k0v = keyuG[base0 + a0]; unsigned i0 = idxG[base0 + a0];
      unsigned k1v = keyuG[base1 + a1]; unsigned i1 = idxG[base1 + a1];
      bool take0 = (h1 >= KK) ||
                   ((h0 < KK) && (k0v < k1v || (k0v == k1v && i0 < i1)));
      sidx[t * KK + k] = take0 ? (int)i0 : (int)i1;
      if (take0) h0++; else h1++;
    }
  }
  int l = t & 63, w = t >> 6;
  float sc = gamma[l] * rsqrtf(rvar[l] + EPSV);
  float tt = fmaf(-rmean[l], sc, beta[l]);
  __syncthreads();
  const float* y2b = y2 + (size_t)b * NN * NO;
  for (int rr = 0; rr < 16; ++rr) {
    int row = w * 16 + rr;
    float v1 = y1[((size_t)b * NN + gr0 + row) * NO + l];
    int mk[KK];
    #pragma unroll
    for (int k = 0; k < KK; ++k) mk[k] = sidx[row * KK + k];
    float vv[KK];
    #pragma unroll
    for (int k = 0; k < KK; ++k) vv[k] = y2b[(size_t)mk[k] * NO + l];  // 20 in flight
    float best = -3.4e38f;
    #pragma unroll
    for (int k = 0; k < KK; ++k) {
      float v = v1 + vv[k];
      v = fmaf(v, sc, tt);
      v = v >= 0.f ? v : SLOPE * v;
      best = fmaxf(best, v);
    }
    ot[l * 65 + row] = best;
  }
  __syncthreads();
  float* ob = out + (size_t)b * NO * NN;
  for (int i = t; i < 4096; i += 256) {
    int o = i >> 6, n = i & 63;
    ob[(size_t)o * NN + gr0 + n] = ot[o * 65 + n];  // coalesced
  }
}

extern "C" void kernel_launch(void* const* d_in, const int* in_sizes, int n_in,
                              void* d_out, int out_size, void* d_ws, size_t ws_size,
                              hipStream_t stream) {
  const float* x     = (const float*)d_in[0];
  const float* W     = (const float*)d_in[1];
  const float* gamma = (const float*)d_in[2];
  const float* beta  = (const float*)d_in[3];
  const float* rmean = (const float*)d_in[4];
  const float* rvar  = (const float*)d_in[5];
  float* ws  = (float*)d_ws;
  float* y1    = ws;
  float* y2    = ws + 2097152;
  float* xx    = ws + 4194304;
  unsigned* keyu = (unsigned*)(ws + 4227072);
  unsigned short* idxu = (unsigned short*)(ws + 5537792);
  float* wa    = ws + 6193152;
  float* wb    = ws + 6197248;
  unsigned short* xThi  = (unsigned short*)(ws + 6201344);
  unsigned short* xTmid = (unsigned short*)(ws + 7249920);
  unsigned short* xTlo  = (unsigned short*)(ws + 8298496);
  float* out = (float*)d_out;

  hipLaunchKernelGGL(k0_wprep, dim3(1),    dim3(256), 0, stream, W, wa, wb);
  hipLaunchKernelGGL(k1_feat,  dim3(512),  dim3(256), 0, stream, x, wa, wb, y1, y2, xx,
                     xThi, xTmid, xTlo);
  hipLaunchKernelGGL(k2_topk,  dim3(1024), dim3(256), 0, stream, xThi, xTmid, xTlo,
                     xx, keyu, idxu);
  hipLaunchKernelGGL(k3_out,   dim3(512),  dim3(256), 0, stream, y1, y2, keyu, idxu,
                     gamma, beta, rmean, rvar, out);
}

// Round 14
// 360.605 us; speedup vs baseline: 1.1524x; 1.0455x over previous
//
#include <hip/hip_runtime.h>

#define NB 8
#define NC 64
#define NN 4096
#define NO 64
#define KK 20
#define EPSV 1e-5f
#define SLOPE 0.2f

typedef __attribute__((ext_vector_type(8))) short short8x;
typedef __attribute__((ext_vector_type(4))) float float4x;

// ws layout (float words):
// y1   : [B][N][O]            @0         2097152
// y2   : [B][N][O]            @2097152   2097152
// xx   : [B][N]               @4194304   32768
// keyu : [B][N][2][20] u32    @4227072   1310720
// idxu : [B][N][2][20] u16    @5537792   655360 words
// wa   : [C][O]               @6193152   4096
// wb   : [C][O]               @6197248   4096
// xThi : [B][N][C] bf16       @6201344   1048576
// xTmid: [B][N][C] bf16       @7249920   1048576
// xTlo : [B][N][C] bf16       @8298496   1048576

__device__ __forceinline__ unsigned short bfh(float f) {  // fp32 -> bf16 (RNE)
  unsigned u = __float_as_uint(f);
  unsigned r = u + 0x7FFFu + ((u >> 16) & 1u);
  return (unsigned short)(r >> 16);
}

__device__ __forceinline__ unsigned flipf(float f) {
  unsigned u = __float_as_uint(f);
  return u ^ ((unsigned)((int)u >> 31) | 0x80000000u);
}

// inverse of flipf, on raw flipped bits -> float bits
__device__ __forceinline__ unsigned unflipu(unsigned v) {
  return v ^ (0x80000000u | (unsigned)((int)(~v) >> 31));
}

__global__ void k0_wprep(const float* __restrict__ W,
                         float* __restrict__ wa, float* __restrict__ wb) {
  int t = threadIdx.x;
  for (int i = t; i < NC * NO; i += 256) {
    int o = i & 63, c = i >> 6;
    float w1 = W[o * 128 + c];
    float w2 = W[o * 128 + 64 + c];
    wa[i] = w1 - w2;  // [c][o]
    wb[i] = w2;
  }
}

// R22: y-loop register-tiled. k1 was LDS-issue-bound: 3072 scalar LDS reads
// per thread (wa/wb re-read 16x redundantly across j). Now: c-chunks of 8
// hold waR/wbR in regs (128 b32 total), and rows remap n=4j+w -> n=16w+j so
// the xs read is a wave-uniform broadcast float4 (256 b128 total).
// Per-accumulator c-order stays exactly 0..63 -> y1/y2 BIT-IDENTICAL.
__global__ __launch_bounds__(256) void k1_feat(const float* __restrict__ x,
    const float* __restrict__ waT, const float* __restrict__ wbT,
    float* __restrict__ y1, float* __restrict__ y2, float* __restrict__ xxg,
    unsigned short* __restrict__ xThi, unsigned short* __restrict__ xTmid,
    unsigned short* __restrict__ xTlo) {
  __shared__ __align__(16) float xs[NC * 68];   // [c][n] stride 68
  __shared__ __align__(16) float wa[NC * NO];
  __shared__ __align__(16) float wb[NC * NO];
  int t = threadIdx.x;
  int b = blockIdx.x >> 6;
  int gr0 = (blockIdx.x & 63) << 6;
  const float* xb = x + (size_t)b * NC * NN;
  #pragma unroll
  for (int k = 0; k < 4; ++k) {
    int i4 = t + k * 256;
    int c = i4 >> 4, col4 = (i4 & 15) << 2;
    *(float4*)&xs[c * 68 + col4] = *(const float4*)&xb[(size_t)c * NN + gr0 + col4];
    *(float4*)&wa[c * 64 + col4] = *(const float4*)&waT[c * 64 + col4];
    *(float4*)&wb[c * 64 + col4] = *(const float4*)&wbT[c * 64 + col4];
  }
  __syncthreads();
  if (t < 64) {
    float s = 0.f;
    #pragma unroll
    for (int c = 0; c < NC; ++c) { float v = xs[c * 68 + t]; s = fmaf(v, v, s); }
    xxg[b * NN + gr0 + t] = s;
  }
  int o = t & 63, w = t >> 6;
  float a1[16], a2[16];
  #pragma unroll
  for (int j = 0; j < 16; ++j) { a1[j] = 0.f; a2[j] = 0.f; }
  #pragma unroll
  for (int c0 = 0; c0 < NC; c0 += 8) {
    float waR[8], wbR[8];
    #pragma unroll
    for (int cc = 0; cc < 8; ++cc) {
      waR[cc] = wa[(c0 + cc) * 64 + o];
      wbR[cc] = wb[(c0 + cc) * 64 + o];
    }
    #pragma unroll
    for (int cc = 0; cc < 8; ++cc) {
      int c = c0 + cc;
      #pragma unroll
      for (int jg = 0; jg < 4; ++jg) {
        float4 xv4 = *(const float4*)&xs[c * 68 + 16 * w + 4 * jg];  // broadcast
        const float* xp = (const float*)&xv4;
        #pragma unroll
        for (int e = 0; e < 4; ++e) {
          a1[4 * jg + e] = fmaf(waR[cc], xp[e], a1[4 * jg + e]);
          a2[4 * jg + e] = fmaf(wbR[cc], xp[e], a2[4 * jg + e]);
        }
      }
    }
  }
  #pragma unroll
  for (int j = 0; j < 16; ++j) {
    int n = 16 * w + j;
    size_t base = ((size_t)b * NN + gr0 + n) * NO + o;
    y1[base] = a1[j];   // coalesced across o
    y2[base] = a2[j];
  }
  // 3-level bf16 split (REQUIRED: 2-level flips top-K selections, R10 failed),
  // transposed layout xT[b][n][c]
  int n2 = t >> 2, c0s = (t & 3) << 4;
  short8x vh[2], vm[2], vl[2];
  #pragma unroll
  for (int i = 0; i < 16; ++i) {
    float v = xs[(c0s + i) * 68 + n2];
    unsigned short h = bfh(v);
    float hf = __uint_as_float((unsigned)h << 16);
    float r1 = v - hf;
    unsigned short md = bfh(r1);
    float mf = __uint_as_float((unsigned)md << 16);
    unsigned short lo = bfh(r1 - mf);
    vh[i >> 3][i & 7] = (short)h;
    vm[i >> 3][i & 7] = (short)md;
    vl[i >> 3][i & 7] = (short)lo;
  }
  size_t tb = ((size_t)(b * NN + gr0 + n2)) * 64 + c0s;
  *(short8x*)&xThi[tb] = vh[0];  *(short8x*)&xThi[tb + 8] = vh[1];
  *(short8x*)&xTmid[tb] = vm[0]; *(short8x*)&xTmid[tb + 8] = vm[1];
  *(short8x*)&xTlo[tb] = vl[0];  *(short8x*)&xTlo[tb + 8] = vl[1];
}

// ----- MFMA split-bf16 Gram + per-row exact top-K (column half) -----
// grid 1024: blk = b*128 + rowgroup*2 + half (R7-proven ordering, 34MB fetch)
//
// k2 FROZEN at R15 (278us). Session ledger:
//   R12 (291us): padded candU scan. R13: spill. R14 (305us): occupancy stuck.
//   R15 (278us, BEST): lane-local keys via swapped MFMA; VGPR 64, occ 33.5%.
//   R16 (292us): DMA staging -> VGPR 80 occupancy cliff (>=68 => 25.7%).
//   R17 (290us): one-barrier dbuf -> not staging-latency-bound.
//   R18 (282us): 8-wave/128-row, occ 37% -> no gain (VALU-issue-bound).
//   R19 (322us)/R20 (310us): MFMA-loop reshapes -> schedule perturbation.
// Structural constraint: k2 is VALU-issue-bound in wave-serialized exact
// top-K maintenance (K=20 in regs) + barrier-locked staging at the 33.5%
// occupancy the 64-VGPR budget allows. VALU-busy time ~188us invariant;
// every MFMA-loop reshape loses more to compiler schedule perturbation than
// the VALU cut saves. R15's exact code shape is load-bearing. DO NOT TOUCH.
__global__ __launch_bounds__(256, 3) void k2_topk(
    const unsigned short* __restrict__ xThi, const unsigned short* __restrict__ xTmid,
    const unsigned short* __restrict__ xTlo, const float* __restrict__ xxg,
    unsigned* __restrict__ keyuG, unsigned short* __restrict__ idxG) {
  __shared__ __align__(16) unsigned short Rb[3 * 4096];  // 24KB staging hi/mid/lo;
                                                         // merge M u64[32*84]=21.5KB aliases
  __shared__ __align__(16) float xxs[64];

  int t = threadIdx.x;
  int blk = blockIdx.x;
  int b = blk >> 7;
  int rem = blk & 127;
  int rg = rem >> 1, half = rem & 1;
  int gr0 = rg << 6;
  int gc0 = half << 11;
  int w = t >> 6;                               // wave
  int lm = t & 15;                              // lane&15 -> row n = 16w+lm
  int quad = (t >> 4) & 3;                      // quarter: owns m ≡ 4q..4q+3 (mod 16)

  // persistent A-fragments (rows gr0+16w+lm, 3 levels x 2 k-steps)
  size_t abase = ((size_t)(b * NN + gr0 + 16 * w + lm)) * 64;
  short8x Ah[2], Am[2], Al[2];
  #pragma unroll
  for (int ks = 0; ks < 2; ++ks) {
    int co = ks * 32 + quad * 8;
    Ah[ks] = *(const short8x*)&xThi[abase + co];
    Am[ks] = *(const short8x*)&xTmid[abase + co];
    Al[ks] = *(const short8x*)&xTlo[abase + co];
  }

  unsigned long long lst[KK];                   // packed (flip(key)<<12)|m
  #pragma unroll
  for (int j = 0; j < KK; ++j) lst[j] = ~0ull;

  size_t bbase = (size_t)(b * NN) * 64;

  for (int mt = 0; mt < 32; ++mt) {
    int gm0 = gc0 + (mt << 6);
    __syncthreads();  // (A) prev tile's Rb/xxs reads done
    #pragma unroll
    for (int lvl = 0; lvl < 3; ++lvl) {
      const unsigned short* src = (lvl == 0) ? xThi : (lvl == 1) ? xTmid : xTlo;
      unsigned short* dst = Rb + lvl * 4096;
      #pragma unroll
      for (int p = 0; p < 2; ++p) {
        int idx = p * 256 + t;
        int n = idx >> 3, o = idx & 7;
        *(short8x*)&dst[n * 64 + ((o + n) & 7) * 8] =
            *(const short8x*)&src[bbase + (size_t)(gm0 + n) * 64 + o * 8];
      }
    }
    if (t < 16) *(float4*)&xxs[t * 4] = *(const float4*)&xxg[b * NN + gm0 + t * 4];
    __syncthreads();  // (B) Rb + xxs ready

    float4x acc[4];
    #pragma unroll
    for (int j = 0; j < 4; ++j) acc[j] = (float4x){0.f, 0.f, 0.f, 0.f};

    const unsigned short* RbH = Rb;
    const unsigned short* RbM = Rb + 4096;
    const unsigned short* RbL = Rb + 8192;
    #pragma unroll
    for (int ks = 0; ks < 2; ++ks) {
      #pragma unroll
      for (int j = 0; j < 4; ++j) {
        int n = 16 * j + lm;
        int off = n * 64 + ((ks * 4 + quad + n) & 7) * 8;
        short8x bh = *(const short8x*)&RbH[off];
        short8x bm = *(const short8x*)&RbM[off];
        short8x bl = *(const short8x*)&RbL[off];
        // swapped operand order (R13): D col=lane&15 = n-row, row = m-col.
        // Same product pairs/order as before -> bit-identical sums.
        acc[j] = __builtin_amdgcn_mfma_f32_16x16x32_bf16(bm, Am[ks], acc[j], 0, 0, 0);
        acc[j] = __builtin_amdgcn_mfma_f32_16x16x32_bf16(bl, Ah[ks], acc[j], 0, 0, 0);
        acc[j] = __builtin_amdgcn_mfma_f32_16x16x32_bf16(bh, Al[ks], acc[j], 0, 0, 0);
        acc[j] = __builtin_amdgcn_mfma_f32_16x16x32_bf16(bm, Ah[ks], acc[j], 0, 0, 0);
        acc[j] = __builtin_amdgcn_mfma_f32_16x16x32_bf16(bh, Am[ks], acc[j], 0, 0, 0);
        acc[j] = __builtin_amdgcn_mfma_f32_16x16x32_bf16(bh, Ah[ks], acc[j], 0, 0, 0);
      }
    }

    // per-lane: acc[j][q] = Gram(n = gr0+16w+lm, m = gm0 + 16j + 4*quad + q)
    // threshold: min over the row's 4 quad-lanes of own 20th-best (float dom.)
    unsigned own19u = (unsigned)(lst[KK - 1] >> 12);
    own19u = min(own19u, 0xFF7FFFFFu);  // clamp sentinel -> FLT_MAX, not NaN
    float thr = __uint_as_float(unflipu(own19u));
    thr = fminf(thr, __shfl_xor(thr, 16));
    thr = fminf(thr, __shfl_xor(thr, 32));

    // mask only -- keys are NOT materialized (recomputed on the rare pop path)
    unsigned mask = 0;
    #pragma unroll
    for (int j = 0; j < 4; ++j) {
      float4 xq = *(const float4*)&xxs[16 * j + 4 * quad];  // broadcast b128
      const float* xqp = (const float*)&xq;
      #pragma unroll
      for (int q = 0; q < 4; ++q) {
        float kv = fmaf(-2.f, acc[j][q], xqp[q]);
        mask |= (unsigned)(kv <= thr) << (4 * j + q);
      }
    }

    // rare path, SINGLE insert site: row-level bound guarantees any
    // final-top-20 candidate passes; exact u64 check rejects extras.
    // key recomputed: 15-cndmask mux over acc + xxs[c] re-read (c = xxs idx).
    while (mask) {
      int e = __builtin_ctz(mask);
      mask &= mask - 1;
      float a00 = (e & 1) ? acc[0][1] : acc[0][0];
      float a01 = (e & 1) ? acc[0][3] : acc[0][2];
      float a10 = (e & 1) ? acc[1][1] : acc[1][0];
      float a11 = (e & 1) ? acc[1][3] : acc[1][2];
      float a20 = (e & 1) ? acc[2][1] : acc[2][0];
      float a21 = (e & 1) ? acc[2][3] : acc[2][2];
      float a30 = (e & 1) ? acc[3][1] : acc[3][0];
      float a31 = (e & 1) ? acc[3][3] : acc[3][2];
      float b0 = (e & 2) ? a01 : a00;
      float b1 = (e & 2) ? a11 : a10;
      float b2 = (e & 2) ? a21 : a20;
      float b3 = (e & 2) ? a31 : a30;
      float c0v = (e & 4) ? b1 : b0;
      float c1v = (e & 4) ? b3 : b2;
      float av = (e & 8) ? c1v : c0v;
      int c = ((e & 12) << 2) | (quad << 2) | (e & 3);  // = m_local = xxs idx
      float kv = fmaf(-2.f, av, xxs[c]);
      unsigned ku = flipf(kv);
      unsigned long long p = ((unsigned long long)ku << 12) | (unsigned)(gm0 + c);
      if (p < lst[KK - 1]) {
        #pragma unroll
        for (int jj = KK - 1; jj >= 1; --jj) {
          bool sh = p < lst[jj - 1];
          unsigned long long cur = (p < lst[jj]) ? p : lst[jj];
          lst[jj] = sh ? lst[jj - 1] : cur;
        }
        if (p < lst[0]) lst[0] = p;
      }
    }
  }

  // two-phase merge (rows 0-31, then 32-63): M = u64[32][84] aliases Rb (dead now)
  int orow = 16 * w + lm, oq = quad;            // owner (row, quarter)
  unsigned long long* M = (unsigned long long*)Rb;
  #pragma unroll 1
  for (int ph = 0; ph < 2; ++ph) {
    __syncthreads();
    if ((orow >> 5) == ph) {
      int r5 = orow & 31;
      #pragma unroll
      for (int k = 0; k < KK; ++k) M[r5 * 84 + oq * 21 + k] = lst[k];
      M[r5 * 84 + oq * 21 + KK] = ~0ull;
    }
    __syncthreads();
    if (t < 32) {
      int h0 = 0, h1 = 0, h2 = 0, h3 = 0;
      int rb = t * 84;
      int row = ph * 32 + t;
      size_t base = ((size_t)(b * NN + gr0 + row) * 2 + half) * KK;
      for (int k = 0; k < KK; ++k) {
        unsigned long long v0m = M[rb + h0];
        unsigned long long v1m = M[rb + 21 + h1];
        unsigned long long v2m = M[rb + 42 + h2];
        unsigned long long v3m = M[rb + 63 + h3];
        unsigned long long bv = v0m; int bq = 0;
        if (v1m < bv) { bv = v1m; bq = 1; }
        if (v2m < bv) { bv = v2m; bq = 2; }
        if (v3m < bv) { bv = v3m; bq = 3; }
        keyuG[base + k] = (unsigned)(bv >> 12);
        idxG[base + k] = (unsigned short)(bv & 0xFFFu);
        if (bq == 0) h0++; else if (bq == 1) h1++; else if (bq == 2) h2++; else h3++;
      }
    }
  }
}

__global__ __launch_bounds__(256) void k3_out(const float* __restrict__ y1,
    const float* __restrict__ y2, const unsigned* __restrict__ keyuG,
    const unsigned short* __restrict__ idxG,
    const float* __restrict__ gamma, const float* __restrict__ beta,
    const float* __restrict__ rmean, const float* __restrict__ rvar,
    float* __restrict__ out) {
  __shared__ int sidx[64 * KK];
  __shared__ float ot[64 * 65];  // [o][n], pad 65
  int t = threadIdx.x;
  int b = blockIdx.x >> 6;
  int gr0 = (blockIdx.x & 63) << 6;
  if (t < 64) {  // 2-way merge of column-half lists
    size_t base0 = ((size_t)(b * NN + gr0 + t) * 2) * KK;
    size_t base1 = base0 + KK;
    int h0 = 0, h1 = 0;
    for (int k = 0; k < KK; ++k) {
      int a0 = h0 < KK ? h0 : KK - 1;
      int a1 = h1 < KK ? h1 : KK - 1;
      unsigned k0v = keyuG[base0 + a0]; unsigned i0 = idxG[base0 + a0];
      unsigned k1v = keyuG[base1 + a1]; unsigned i1 = idxG[base1 + a1];
      bool take0 = (h1 >= KK) ||
                   ((h0 < KK) && (k0v < k1v || (k0v == k1v && i0 < i1)));
      sidx[t * KK + k] = take0 ? (int)i0 : (int)i1;
      if (take0) h0++; else h1++;
    }
  }
  int l = t & 63, w = t >> 6;
  float sc = gamma[l] * rsqrtf(rvar[l] + EPSV);
  float tt = fmaf(-rmean[l], sc, beta[l]);
  __syncthreads();
  const float* y2b = y2 + (size_t)b * NN * NO;
  for (int rr = 0; rr < 16; ++rr) {
    int row = w * 16 + rr;
    float v1 = y1[((size_t)b * NN + gr0 + row) * NO + l];
    int mk[KK];
    #pragma unroll
    for (int k = 0; k < KK; ++k) mk[k] = sidx[row * KK + k];
    float vv[KK];
    #pragma unroll
    for (int k = 0; k < KK; ++k) vv[k] = y2b[(size_t)mk[k] * NO + l];  // 20 in flight
    float best = -3.4e38f;
    #pragma unroll
    for (int k = 0; k < KK; ++k) {
      float v = v1 + vv[k];
      v = fmaf(v, sc, tt);
      v = v >= 0.f ? v : SLOPE * v;
      best = fmaxf(best, v);
    }
    ot[l * 65 + row] = best;
  }
  __syncthreads();
  float* ob = out + (size_t)b * NO * NN;
  for (int i = t; i < 4096; i += 256) {
    int o = i >> 6, n = i & 63;
    ob[(size_t)o * NN + gr0 + n] = ot[o * 65 + n];  // coalesced
  }
}

extern "C" void kernel_launch(void* const* d_in, const int* in_sizes, int n_in,
                              void* d_out, int out_size, void* d_ws, size_t ws_size,
                              hipStream_t stream) {
  const float* x     = (const float*)d_in[0];
  const float* W     = (const float*)d_in[1];
  const float* gamma = (const float*)d_in[2];
  const float* beta  = (const float*)d_in[3];
  const float* rmean = (const float*)d_in[4];
  const float* rvar  = (const float*)d_in[5];
  float* ws  = (float*)d_ws;
  float* y1    = ws;
  float* y2    = ws + 2097152;
  float* xx    = ws + 4194304;
  unsigned* keyu = (unsigned*)(ws + 4227072);
  unsigned short* idxu = (unsigned short*)(ws + 5537792);
  float* wa    = ws + 6193152;
  float* wb    = ws + 6197248;
  unsigned short* xThi  = (unsigned short*)(ws + 6201344);
  unsigned short* xTmid = (unsigned short*)(ws + 7249920);
  unsigned short* xTlo  = (unsigned short*)(ws + 8298496);
  float* out = (float*)d_out;

  hipLaunchKernelGGL(k0_wprep, dim3(1),    dim3(256), 0, stream, W, wa, wb);
  hipLaunchKernelGGL(k1_feat,  dim3(512),  dim3(256), 0, stream, x, wa, wb, y1, y2, xx,
                     xThi, xTmid, xTlo);
  hipLaunchKernelGGL(k2_topk,  dim3(1024), dim3(256), 0, stream, xThi, xTmid, xTlo,
                     xx, keyu, idxu);
  hipLaunchKernelGGL(k3_out,   dim3(512),  dim3(256), 0, stream, y1, y2, keyu, idxu,
                     gamma, beta, rmean, rvar, out);
}

// Round 15
// 359.676 us; speedup vs baseline: 1.1554x; 1.0026x over previous
//
#include <hip/hip_runtime.h>

#define NB 8
#define NC 64
#define NN 4096
#define NO 64
#define KK 20
#define EPSV 1e-5f
#define SLOPE 0.2f

typedef __attribute__((ext_vector_type(8))) short short8x;
typedef __attribute__((ext_vector_type(4))) float float4x;

// ws layout (float words):
// y1   : [B][N][O]            @0         2097152
// y2   : [B][N][O]            @2097152   2097152
// xx   : [B][N]               @4194304   32768
// keyu : [B][N][2][20] u32    @4227072   1310720
// idxu : [B][N][2][20] u16    @5537792   655360 words
// (wa/wb slots @6193152/@6197248 now unused -- R23 fused k0 into k1)
// xThi : [B][N][C] bf16       @6201344   1048576
// xTmid: [B][N][C] bf16       @7249920   1048576
// xTlo : [B][N][C] bf16       @8298496   1048576

__device__ __forceinline__ unsigned short bfh(float f) {  // fp32 -> bf16 (RNE)
  unsigned u = __float_as_uint(f);
  unsigned r = u + 0x7FFFu + ((u >> 16) & 1u);
  return (unsigned short)(r >> 16);
}

__device__ __forceinline__ unsigned flipf(float f) {
  unsigned u = __float_as_uint(f);
  return u ^ ((unsigned)((int)u >> 31) | 0x80000000u);
}

// inverse of flipf, on raw flipped bits -> float bits
__device__ __forceinline__ unsigned unflipu(unsigned v) {
  return v ^ (0x80000000u | (unsigned)((int)(~v) >> 31));
}

// R22: y-loop register-tiled (k1 was LDS-issue-bound; wa/wb were re-read 16x
// redundantly). c-chunks of 8 hold waR/wbR in regs; rows remap n=4j+w ->
// n=16w+j so the xs read is a wave-uniform broadcast float4.
// R23: k0 DELETED -- each k1 block computes wa/wb from W during staging with
// the IDENTICAL fp32 subtraction k0 used (w1-w2), so y1/y2 are bit-identical.
// W is 32KB -> L2-hot; the scalar loads hide under the x-tile HBM staging.
__global__ __launch_bounds__(256) void k1_feat(const float* __restrict__ x,
    const float* __restrict__ W,
    float* __restrict__ y1, float* __restrict__ y2, float* __restrict__ xxg,
    unsigned short* __restrict__ xThi, unsigned short* __restrict__ xTmid,
    unsigned short* __restrict__ xTlo) {
  __shared__ __align__(16) float xs[NC * 68];   // [c][n] stride 68
  __shared__ __align__(16) float wa[NC * NO];
  __shared__ __align__(16) float wb[NC * NO];
  int t = threadIdx.x;
  int b = blockIdx.x >> 6;
  int gr0 = (blockIdx.x & 63) << 6;
  const float* xb = x + (size_t)b * NC * NN;
  #pragma unroll
  for (int k = 0; k < 4; ++k) {
    int i4 = t + k * 256;
    int c = i4 >> 4, col4 = (i4 & 15) << 2;
    *(float4*)&xs[c * 68 + col4] = *(const float4*)&xb[(size_t)c * NN + gr0 + col4];
    #pragma unroll
    for (int e = 0; e < 4; ++e) {
      int o = col4 + e;
      float w1 = W[o * 128 + c];        // same op order as old k0 -> bit-identical
      float w2 = W[o * 128 + 64 + c];
      wa[c * 64 + o] = w1 - w2;
      wb[c * 64 + o] = w2;
    }
  }
  __syncthreads();
  if (t < 64) {
    float s = 0.f;
    #pragma unroll
    for (int c = 0; c < NC; ++c) { float v = xs[c * 68 + t]; s = fmaf(v, v, s); }
    xxg[b * NN + gr0 + t] = s;
  }
  int o = t & 63, w = t >> 6;
  float a1[16], a2[16];
  #pragma unroll
  for (int j = 0; j < 16; ++j) { a1[j] = 0.f; a2[j] = 0.f; }
  #pragma unroll
  for (int c0 = 0; c0 < NC; c0 += 8) {
    float waR[8], wbR[8];
    #pragma unroll
    for (int cc = 0; cc < 8; ++cc) {
      waR[cc] = wa[(c0 + cc) * 64 + o];
      wbR[cc] = wb[(c0 + cc) * 64 + o];
    }
    #pragma unroll
    for (int cc = 0; cc < 8; ++cc) {
      int c = c0 + cc;
      #pragma unroll
      for (int jg = 0; jg < 4; ++jg) {
        float4 xv4 = *(const float4*)&xs[c * 68 + 16 * w + 4 * jg];  // broadcast
        const float* xp = (const float*)&xv4;
        #pragma unroll
        for (int e = 0; e < 4; ++e) {
          a1[4 * jg + e] = fmaf(waR[cc], xp[e], a1[4 * jg + e]);
          a2[4 * jg + e] = fmaf(wbR[cc], xp[e], a2[4 * jg + e]);
        }
      }
    }
  }
  #pragma unroll
  for (int j = 0; j < 16; ++j) {
    int n = 16 * w + j;
    size_t base = ((size_t)b * NN + gr0 + n) * NO + o;
    y1[base] = a1[j];   // coalesced across o
    y2[base] = a2[j];
  }
  // 3-level bf16 split (REQUIRED: 2-level flips top-K selections, R10 failed),
  // transposed layout xT[b][n][c]
  int n2 = t >> 2, c0s = (t & 3) << 4;
  short8x vh[2], vm[2], vl[2];
  #pragma unroll
  for (int i = 0; i < 16; ++i) {
    float v = xs[(c0s + i) * 68 + n2];
    unsigned short h = bfh(v);
    float hf = __uint_as_float((unsigned)h << 16);
    float r1 = v - hf;
    unsigned short md = bfh(r1);
    float mf = __uint_as_float((unsigned)md << 16);
    unsigned short lo = bfh(r1 - mf);
    vh[i >> 3][i & 7] = (short)h;
    vm[i >> 3][i & 7] = (short)md;
    vl[i >> 3][i & 7] = (short)lo;
  }
  size_t tb = ((size_t)(b * NN + gr0 + n2)) * 64 + c0s;
  *(short8x*)&xThi[tb] = vh[0];  *(short8x*)&xThi[tb + 8] = vh[1];
  *(short8x*)&xTmid[tb] = vm[0]; *(short8x*)&xTmid[tb + 8] = vm[1];
  *(short8x*)&xTlo[tb] = vl[0];  *(short8x*)&xTlo[tb + 8] = vl[1];
}

// ----- MFMA split-bf16 Gram + per-row exact top-K (column half) -----
// grid 1024: blk = b*128 + rowgroup*2 + half (R7-proven ordering, 34MB fetch)
//
// k2 FROZEN at R15 (278us). Session ledger:
//   R12 (291us): padded candU scan. R13: spill. R14 (305us): occupancy stuck.
//   R15 (278us, BEST): lane-local keys via swapped MFMA; VGPR 64, occ 33.5%.
//   R16 (292us): DMA staging -> VGPR 80 occupancy cliff (>=68 => 25.7%).
//   R17 (290us): one-barrier dbuf -> not staging-latency-bound.
//   R18 (282us): 8-wave/128-row, occ 37% -> no gain (VALU-issue-bound).
//   R19 (322us)/R20 (310us): MFMA-loop reshapes -> schedule perturbation.
// Structural constraint: k2 is VALU-issue-bound in wave-serialized exact
// top-K maintenance (K=20 in regs) + barrier-locked staging at the 33.5%
// occupancy the 64-VGPR budget allows. VALU-busy time ~188us invariant;
// every MFMA-loop reshape loses more to compiler schedule perturbation than
// the VALU cut saves. R15's exact code shape is load-bearing. DO NOT TOUCH.
__global__ __launch_bounds__(256, 3) void k2_topk(
    const unsigned short* __restrict__ xThi, const unsigned short* __restrict__ xTmid,
    const unsigned short* __restrict__ xTlo, const float* __restrict__ xxg,
    unsigned* __restrict__ keyuG, unsigned short* __restrict__ idxG) {
  __shared__ __align__(16) unsigned short Rb[3 * 4096];  // 24KB staging hi/mid/lo;
                                                         // merge M u64[32*84]=21.5KB aliases
  __shared__ __align__(16) float xxs[64];

  int t = threadIdx.x;
  int blk = blockIdx.x;
  int b = blk >> 7;
  int rem = blk & 127;
  int rg = rem >> 1, half = rem & 1;
  int gr0 = rg << 6;
  int gc0 = half << 11;
  int w = t >> 6;                               // wave
  int lm = t & 15;                              // lane&15 -> row n = 16w+lm
  int quad = (t >> 4) & 3;                      // quarter: owns m ≡ 4q..4q+3 (mod 16)

  // persistent A-fragments (rows gr0+16w+lm, 3 levels x 2 k-steps)
  size_t abase = ((size_t)(b * NN + gr0 + 16 * w + lm)) * 64;
  short8x Ah[2], Am[2], Al[2];
  #pragma unroll
  for (int ks = 0; ks < 2; ++ks) {
    int co = ks * 32 + quad * 8;
    Ah[ks] = *(const short8x*)&xThi[abase + co];
    Am[ks] = *(const short8x*)&xTmid[abase + co];
    Al[ks] = *(const short8x*)&xTlo[abase + co];
  }

  unsigned long long lst[KK];                   // packed (flip(key)<<12)|m
  #pragma unroll
  for (int j = 0; j < KK; ++j) lst[j] = ~0ull;

  size_t bbase = (size_t)(b * NN) * 64;

  for (int mt = 0; mt < 32; ++mt) {
    int gm0 = gc0 + (mt << 6);
    __syncthreads();  // (A) prev tile's Rb/xxs reads done
    #pragma unroll
    for (int lvl = 0; lvl < 3; ++lvl) {
      const unsigned short* src = (lvl == 0) ? xThi : (lvl == 1) ? xTmid : xTlo;
      unsigned short* dst = Rb + lvl * 4096;
      #pragma unroll
      for (int p = 0; p < 2; ++p) {
        int idx = p * 256 + t;
        int n = idx >> 3, o = idx & 7;
        *(short8x*)&dst[n * 64 + ((o + n) & 7) * 8] =
            *(const short8x*)&src[bbase + (size_t)(gm0 + n) * 64 + o * 8];
      }
    }
    if (t < 16) *(float4*)&xxs[t * 4] = *(const float4*)&xxg[b * NN + gm0 + t * 4];
    __syncthreads();  // (B) Rb + xxs ready

    float4x acc[4];
    #pragma unroll
    for (int j = 0; j < 4; ++j) acc[j] = (float4x){0.f, 0.f, 0.f, 0.f};

    const unsigned short* RbH = Rb;
    const unsigned short* RbM = Rb + 4096;
    const unsigned short* RbL = Rb + 8192;
    #pragma unroll
    for (int ks = 0; ks < 2; ++ks) {
      #pragma unroll
      for (int j = 0; j < 4; ++j) {
        int n = 16 * j + lm;
        int off = n * 64 + ((ks * 4 + quad + n) & 7) * 8;
        short8x bh = *(const short8x*)&RbH[off];
        short8x bm = *(const short8x*)&RbM[off];
        short8x bl = *(const short8x*)&RbL[off];
        // swapped operand order (R13): D col=lane&15 = n-row, row = m-col.
        // Same product pairs/order as before -> bit-identical sums.
        acc[j] = __builtin_amdgcn_mfma_f32_16x16x32_bf16(bm, Am[ks], acc[j], 0, 0, 0);
        acc[j] = __builtin_amdgcn_mfma_f32_16x16x32_bf16(bl, Ah[ks], acc[j], 0, 0, 0);
        acc[j] = __builtin_amdgcn_mfma_f32_16x16x32_bf16(bh, Al[ks], acc[j], 0, 0, 0);
        acc[j] = __builtin_amdgcn_mfma_f32_16x16x32_bf16(bm, Ah[ks], acc[j], 0, 0, 0);
        acc[j] = __builtin_amdgcn_mfma_f32_16x16x32_bf16(bh, Am[ks], acc[j], 0, 0, 0);
        acc[j] = __builtin_amdgcn_mfma_f32_16x16x32_bf16(bh, Ah[ks], acc[j], 0, 0, 0);
      }
    }

    // per-lane: acc[j][q] = Gram(n = gr0+16w+lm, m = gm0 + 16j + 4*quad + q)
    // threshold: min over the row's 4 quad-lanes of own 20th-best (float dom.)
    unsigned own19u = (unsigned)(lst[KK - 1] >> 12);
    own19u = min(own19u, 0xFF7FFFFFu);  // clamp sentinel -> FLT_MAX, not NaN
    float thr = __uint_as_float(unflipu(own19u));
    thr = fminf(thr, __shfl_xor(thr, 16));
    thr = fminf(thr, __shfl_xor(thr, 32));

    // mask only -- keys are NOT materialized (recomputed on the rare pop path)
    unsigned mask = 0;
    #pragma unroll
    for (int j = 0; j < 4; ++j) {
      float4 xq = *(const float4*)&xxs[16 * j + 4 * quad];  // broadcast b128
      const float* xqp = (const float*)&xq;
      #pragma unroll
      for (int q = 0; q < 4; ++q) {
        float kv = fmaf(-2.f, acc[j][q], xqp[q]);
        mask |= (unsigned)(kv <= thr) << (4 * j + q);
      }
    }

    // rare path, SINGLE insert site: row-level bound guarantees any
    // final-top-20 candidate passes; exact u64 check rejects extras.
    // key recomputed: 15-cndmask mux over acc + xxs[c] re-read (c = xxs idx).
    while (mask) {
      int e = __builtin_ctz(mask);
      mask &= mask - 1;
      float a00 = (e & 1) ? acc[0][1] : acc[0][0];
      float a01 = (e & 1) ? acc[0][3] : acc[0][2];
      float a10 = (e & 1) ? acc[1][1] : acc[1][0];
      float a11 = (e & 1) ? acc[1][3] : acc[1][2];
      float a20 = (e & 1) ? acc[2][1] : acc[2][0];
      float a21 = (e & 1) ? acc[2][3] : acc[2][2];
      float a30 = (e & 1) ? acc[3][1] : acc[3][0];
      float a31 = (e & 1) ? acc[3][3] : acc[3][2];
      float b0 = (e & 2) ? a01 : a00;
      float b1 = (e & 2) ? a11 : a10;
      float b2 = (e & 2) ? a21 : a20;
      float b3 = (e & 2) ? a31 : a30;
      float c0v = (e & 4) ? b1 : b0;
      float c1v = (e & 4) ? b3 : b2;
      float av = (e & 8) ? c1v : c0v;
      int c = ((e & 12) << 2) | (quad << 2) | (e & 3);  // = m_local = xxs idx
      float kv = fmaf(-2.f, av, xxs[c]);
      unsigned ku = flipf(kv);
      unsigned long long p = ((unsigned long long)ku << 12) | (unsigned)(gm0 + c);
      if (p < lst[KK - 1]) {
        #pragma unroll
        for (int jj = KK - 1; jj >= 1; --jj) {
          bool sh = p < lst[jj - 1];
          unsigned long long cur = (p < lst[jj]) ? p : lst[jj];
          lst[jj] = sh ? lst[jj - 1] : cur;
        }
        if (p < lst[0]) lst[0] = p;
      }
    }
  }

  // two-phase merge (rows 0-31, then 32-63): M = u64[32][84] aliases Rb (dead now)
  int orow = 16 * w + lm, oq = quad;            // owner (row, quarter)
  unsigned long long* M = (unsigned long long*)Rb;
  #pragma unroll 1
  for (int ph = 0; ph < 2; ++ph) {
    __syncthreads();
    if ((orow >> 5) == ph) {
      int r5 = orow & 31;
      #pragma unroll
      for (int k = 0; k < KK; ++k) M[r5 * 84 + oq * 21 + k] = lst[k];
      M[r5 * 84 + oq * 21 + KK] = ~0ull;
    }
    __syncthreads();
    if (t < 32) {
      int h0 = 0, h1 = 0, h2 = 0, h3 = 0;
      int rb = t * 84;
      int row = ph * 32 + t;
      size_t base = ((size_t)(b * NN + gr0 + row) * 2 + half) * KK;
      for (int k = 0; k < KK; ++k) {
        unsigned long long v0m = M[rb + h0];
        unsigned long long v1m = M[rb + 21 + h1];
        unsigned long long v2m = M[rb + 42 + h2];
        unsigned long long v3m = M[rb + 63 + h3];
        unsigned long long bv = v0m; int bq = 0;
        if (v1m < bv) { bv = v1m; bq = 1; }
        if (v2m < bv) { bv = v2m; bq = 2; }
        if (v3m < bv) { bv = v3m; bq = 3; }
        keyuG[base + k] = (unsigned)(bv >> 12);
        idxG[base + k] = (unsigned short)(bv & 0xFFFu);
        if (bq == 0) h0++; else if (bq == 1) h1++; else if (bq == 2) h2++; else h3++;
      }
    }
  }
}

__global__ __launch_bounds__(256) void k3_out(const float* __restrict__ y1,
    const float* __restrict__ y2, const unsigned* __restrict__ keyuG,
    const unsigned short* __restrict__ idxG,
    const float* __restrict__ gamma, const float* __restrict__ beta,
    const float* __restrict__ rmean, const float* __restrict__ rvar,
    float* __restrict__ out) {
  __shared__ int sidx[64 * KK];
  __shared__ float ot[64 * 65];  // [o][n], pad 65
  int t = threadIdx.x;
  int b = blockIdx.x >> 6;
  int gr0 = (blockIdx.x & 63) << 6;
  if (t < 64) {  // 2-way merge of column-half lists
    size_t base0 = ((size_t)(b * NN + gr0 + t) * 2) * KK;
    size_t base1 = base0 + KK;
    int h0 = 0, h1 = 0;
    for (int k = 0; k < KK; ++k) {
      int a0 = h0 < KK ? h0 : KK - 1;
      int a1 = h1 < KK ? h1 : KK - 1;
      unsigned k0v = keyuG[base0 + a0]; unsigned i0 = idxG[base0 + a0];
      unsigned k1v = keyuG[base1 + a1]; unsigned i1 = idxG[base1 + a1];
      bool take0 = (h1 >= KK) ||
                   ((h0 < KK) && (k0v < k1v || (k0v == k1v && i0 < i1)));
      sidx[t * KK + k] = take0 ? (int)i0 : (int)i1;
      if (take0) h0++; else h1++;
    }
  }
  int l = t & 63, w = t >> 6;
  float sc = gamma[l] * rsqrtf(rvar[l] + EPSV);
  float tt = fmaf(-rmean[l], sc, beta[l]);
  __syncthreads();
  const float* y2b = y2 + (size_t)b * NN * NO;
  for (int rr = 0; rr < 16; ++rr) {
    int row = w * 16 + rr;
    float v1 = y1[((size_t)b * NN + gr0 + row) * NO + l];
    int mk[KK];
    #pragma unroll
    for (int k = 0; k < KK; ++k) mk[k] = sidx[row * KK + k];
    float vv[KK];
    #pragma unroll
    for (int k = 0; k < KK; ++k) vv[k] = y2b[(size_t)mk[k] * NO + l];  // 20 in flight
    float best = -3.4e38f;
    #pragma unroll
    for (int k = 0; k < KK; ++k) {
      float v = v1 + vv[k];
      v = fmaf(v, sc, tt);
      v = v >= 0.f ? v : SLOPE * v;
      best = fmaxf(best, v);
    }
    ot[l * 65 + row] = best;
  }
  __syncthreads();
  float* ob = out + (size_t)b * NO * NN;
  for (int i = t; i < 4096; i += 256) {
    int o = i >> 6, n = i & 63;
    ob[(size_t)o * NN + gr0 + n] = ot[o * 65 + n];  // coalesced
  }
}

extern "C" void kernel_launch(void* const* d_in, const int* in_sizes, int n_in,
                              void* d_out, int out_size, void* d_ws, size_t ws_size,
                              hipStream_t stream) {
  const float* x     = (const float*)d_in[0];
  const float* W     = (const float*)d_in[1];
  const float* gamma = (const float*)d_in[2];
  const float* beta  = (const float*)d_in[3];
  const float* rmean = (const float*)d_in[4];
  const float* rvar  = (const float*)d_in[5];
  float* ws  = (float*)d_ws;
  float* y1    = ws;
  float* y2    = ws + 2097152;
  float* xx    = ws + 4194304;
  unsigned* keyu = (unsigned*)(ws + 4227072);
  unsigned short* idxu = (unsigned short*)(ws + 5537792);
  unsigned short* xThi  = (unsigned short*)(ws + 6201344);
  unsigned short* xTmid = (unsigned short*)(ws + 7249920);
  unsigned short* xTlo  = (unsigned short*)(ws + 8298496);
  float* out = (float*)d_out;

  hipLaunchKernelGGL(k1_feat,  dim3(512),  dim3(256), 0, stream, x, W, y1, y2, xx,
                     xThi, xTmid, xTlo);
  hipLaunchKernelGGL(k2_topk,  dim3(1024), dim3(256), 0, stream, xThi, xTmid, xTlo,
                     xx, keyu, idxu);
  hipLaunchKernelGGL(k3_out,   dim3(512),  dim3(256), 0, stream, y1, y2, keyu, idxu,
                     gamma, beta, rmean, rvar, out);
}